// Round 1
// baseline (467.913 us; speedup 1.0000x reference)
//
#include <hip/hip_runtime.h>
#include <math.h>

// Problem constants: B=2, N=2048, C=384, H=6, D=64
// All quantized tensors are stored as their INTEGER values (round(clip(x/a)))
// with the alpha scales factored into GEMM epilogues.

__device__ __forceinline__ float qclip(float s) {
  return fminf(fmaxf(s, -128.0f), 127.0f);
}

// ---------------- elementwise quantize (float4) ----------------
__global__ __launch_bounds__(256)
void quant4_kernel(const float* __restrict__ in, float* __restrict__ out,
                   const float* __restrict__ alpha, int n4) {
  int i = blockIdx.x * 256 + threadIdx.x;
  if (i >= n4) return;
  float a = alpha[0];
  float4 v = ((const float4*)in)[i];
  float4 o;
  o.x = rintf(qclip(v.x / a));
  o.y = rintf(qclip(v.y / a));
  o.z = rintf(qclip(v.z / a));
  o.w = rintf(qclip(v.w / a));
  ((float4*)out)[i] = o;
}

// ---------------- QKV GEMM: [4096,384] @ [1152,384]^T ----------------
// epilogue requantizes into q[bh,n,d], k[bh,n,d], vT[bh,d,n] (integer floats)
__global__ __launch_bounds__(256)
void gemm_qkv(const float* __restrict__ A, const float* __restrict__ W,
              float* __restrict__ qws, float* __restrict__ kws,
              float* __restrict__ vwsT,
              const float* __restrict__ aa, const float* __restrict__ aw,
              const float* __restrict__ aq, const float* __restrict__ ak,
              const float* __restrict__ av) {
  __shared__ float As[32][68];
  __shared__ float Bs[32][68];
  const int t = threadIdx.x;
  const int tx = t & 15, ty = t >> 4;
  const int m0 = blockIdx.x * 64, n0 = blockIdx.y * 64;
  float acc[4][4] = {};
  for (int k0 = 0; k0 < 384; k0 += 32) {
#pragma unroll
    for (int u = 0; u < 2; ++u) {
      int s4 = t + u * 256;
      int row = s4 >> 3;
      int col = (s4 & 7) << 2;
      float4 va = *(const float4*)(A + (size_t)(m0 + row) * 384 + k0 + col);
      As[col + 0][row] = va.x; As[col + 1][row] = va.y;
      As[col + 2][row] = va.z; As[col + 3][row] = va.w;
      float4 vb = *(const float4*)(W + (size_t)(n0 + row) * 384 + k0 + col);
      Bs[col + 0][row] = vb.x; Bs[col + 1][row] = vb.y;
      Bs[col + 2][row] = vb.z; Bs[col + 3][row] = vb.w;
    }
    __syncthreads();
#pragma unroll
    for (int kk = 0; kk < 32; ++kk) {
      float4 a4 = *(float4*)(&As[kk][ty << 2]);
      float4 b4 = *(float4*)(&Bs[kk][tx << 2]);
      float ar[4] = {a4.x, a4.y, a4.z, a4.w};
      float br[4] = {b4.x, b4.y, b4.z, b4.w};
#pragma unroll
      for (int r = 0; r < 4; ++r)
#pragma unroll
        for (int c = 0; c < 4; ++c)
          acc[r][c] = fmaf(ar[r], br[c], acc[r][c]);
    }
    __syncthreads();
  }
  const float sAB = aa[0] * aw[0];
  const float vaq = aq[0], vak = ak[0], vav = av[0];
#pragma unroll
  for (int r = 0; r < 4; ++r) {
    int m = m0 + (ty << 2) + r;
    int bb = m >> 11, nn = m & 2047;
#pragma unroll
    for (int c = 0; c < 4; ++c) {
      int cg = n0 + (tx << 2) + c;
      float val = acc[r][c] * sAB;
      int t3 = cg / 384;
      int rem = cg - t3 * 384;
      int h = rem >> 6, d = rem & 63;
      int bh = bb * 6 + h;
      if (t3 == 0) {
        qws[((size_t)(bh * 2048 + nn) << 6) + d] = rintf(qclip(val / vaq));
      } else if (t3 == 1) {
        kws[((size_t)(bh * 2048 + nn) << 6) + d] = rintf(qclip(val / vak));
      } else {
        vwsT[((size_t)((bh << 6) + d) << 11) + nn] = rintf(qclip(val / vav));
      }
    }
  }
}

// ---------------- scores: S = q @ k^T * (aq*ak*0.125), requant -> int8 ----------------
__global__ __launch_bounds__(256)
void gemm_scores(const float* __restrict__ qws, const float* __restrict__ kws,
                 signed char* __restrict__ Sq,
                 const float* __restrict__ aq, const float* __restrict__ ak,
                 const float* __restrict__ aattn) {
  __shared__ float As[32][68];
  __shared__ float Bs[32][68];
  const int t = threadIdx.x;
  const int tx = t & 15, ty = t >> 4;
  const int m0 = blockIdx.x * 64, n0 = blockIdx.y * 64;
  const int bh = blockIdx.z;
  const float* A = qws + ((size_t)bh << 17);
  const float* Bk = kws + ((size_t)bh << 17);
  float acc[4][4] = {};
  for (int k0 = 0; k0 < 64; k0 += 32) {
#pragma unroll
    for (int u = 0; u < 2; ++u) {
      int s4 = t + u * 256;
      int row = s4 >> 3;
      int col = (s4 & 7) << 2;
      float4 va = *(const float4*)(A + (size_t)(m0 + row) * 64 + k0 + col);
      As[col + 0][row] = va.x; As[col + 1][row] = va.y;
      As[col + 2][row] = va.z; As[col + 3][row] = va.w;
      float4 vb = *(const float4*)(Bk + (size_t)(n0 + row) * 64 + k0 + col);
      Bs[col + 0][row] = vb.x; Bs[col + 1][row] = vb.y;
      Bs[col + 2][row] = vb.z; Bs[col + 3][row] = vb.w;
    }
    __syncthreads();
#pragma unroll
    for (int kk = 0; kk < 32; ++kk) {
      float4 a4 = *(float4*)(&As[kk][ty << 2]);
      float4 b4 = *(float4*)(&Bs[kk][tx << 2]);
      float ar[4] = {a4.x, a4.y, a4.z, a4.w};
      float br[4] = {b4.x, b4.y, b4.z, b4.w};
#pragma unroll
      for (int r = 0; r < 4; ++r)
#pragma unroll
        for (int c = 0; c < 4; ++c)
          acc[r][c] = fmaf(ar[r], br[c], acc[r][c]);
    }
    __syncthreads();
  }
  const float sc = aq[0] * ak[0] * 0.125f;
  const float ia = aattn[0];
  signed char* Sb = Sq + ((size_t)bh << 22);
#pragma unroll
  for (int r = 0; r < 4; ++r) {
    size_t rowoff = (size_t)(m0 + (ty << 2) + r) << 11;
#pragma unroll
    for (int c = 0; c < 4; ++c) {
      float sv = acc[r][c] * sc;
      Sb[rowoff + n0 + (tx << 2) + c] = (signed char)(int)rintf(qclip(sv / ia));
    }
  }
}

// ---------------- per-row softmax stats: m = a*max, l = sum exp ----------------
__global__ __launch_bounds__(256)
void softmax_stats(const signed char* __restrict__ Sq, float2* __restrict__ stats,
                   const float* __restrict__ aattn) {
  const int lane = threadIdx.x & 63;
  const int row = (blockIdx.x << 2) + (threadIdx.x >> 6);
  const signed char* p = Sq + ((size_t)row << 11);
  char4 vals[8];
  int vmax = -129;
#pragma unroll
  for (int u = 0; u < 8; ++u) {
    vals[u] = ((const char4*)p)[lane + (u << 6)];
    vmax = max(vmax, (int)vals[u].x);
    vmax = max(vmax, (int)vals[u].y);
    vmax = max(vmax, (int)vals[u].z);
    vmax = max(vmax, (int)vals[u].w);
  }
#pragma unroll
  for (int off = 32; off > 0; off >>= 1)
    vmax = max(vmax, __shfl_xor(vmax, off, 64));
  const float a = aattn[0];
  const float m = a * (float)vmax;
  float l = 0.0f;
#pragma unroll
  for (int u = 0; u < 8; ++u) {
    l += expf(a * (float)vals[u].x - m);
    l += expf(a * (float)vals[u].y - m);
    l += expf(a * (float)vals[u].z - m);
    l += expf(a * (float)vals[u].w - m);
  }
#pragma unroll
  for (int off = 32; off > 0; off >>= 1)
    l += __shfl_xor(l, off, 64);
  if (lane == 0) stats[row] = make_float2(m, l);
}

// ---------------- PV: P (from Sq + stats, requant) @ vT^T, requant -> ows ----------------
__global__ __launch_bounds__(256)
void gemm_pv(const signed char* __restrict__ Sq, const float* __restrict__ vwsT,
             const float2* __restrict__ stats, float* __restrict__ ows,
             const float* __restrict__ aattn, const float* __restrict__ aattn2,
             const float* __restrict__ av, const float* __restrict__ apa) {
  __shared__ float Ps[32][68];
  __shared__ float Vs[32][68];
  __shared__ float2 st[64];
  const int t = threadIdx.x;
  const int tx = t & 15, ty = t >> 4;
  const int i0 = blockIdx.x * 64;
  const int bh = blockIdx.y;
  const float a = aattn[0];
  const float a2 = aattn2[0];
  if (t < 64) st[t] = stats[(bh << 11) + i0 + t];
  __syncthreads();
  const signed char* Sb = Sq + ((size_t)bh << 22);
  const float* Vb = vwsT + ((size_t)bh << 17);
  float acc[4][4] = {};
  for (int j0 = 0; j0 < 2048; j0 += 32) {
#pragma unroll
    for (int u = 0; u < 2; ++u) {
      int s4 = t + u * 256;
      int row = s4 >> 3;
      int col = (s4 & 7) << 2;
      char4 sc4 = *(const char4*)(Sb + ((size_t)(i0 + row) << 11) + j0 + col);
      float2 ml = st[row];
      Ps[col + 0][row] = rintf(qclip(expf(a * (float)sc4.x - ml.x) / ml.y / a2));
      Ps[col + 1][row] = rintf(qclip(expf(a * (float)sc4.y - ml.x) / ml.y / a2));
      Ps[col + 2][row] = rintf(qclip(expf(a * (float)sc4.z - ml.x) / ml.y / a2));
      Ps[col + 3][row] = rintf(qclip(expf(a * (float)sc4.w - ml.x) / ml.y / a2));
      float4 vv = *(const float4*)(Vb + ((size_t)row << 11) + j0 + col);
      Vs[col + 0][row] = vv.x; Vs[col + 1][row] = vv.y;
      Vs[col + 2][row] = vv.z; Vs[col + 3][row] = vv.w;
    }
    __syncthreads();
#pragma unroll
    for (int kk = 0; kk < 32; ++kk) {
      float4 a4 = *(float4*)(&Ps[kk][ty << 2]);
      float4 b4 = *(float4*)(&Vs[kk][tx << 2]);
      float ar[4] = {a4.x, a4.y, a4.z, a4.w};
      float br[4] = {b4.x, b4.y, b4.z, b4.w};
#pragma unroll
      for (int r = 0; r < 4; ++r)
#pragma unroll
        for (int c = 0; c < 4; ++c)
          acc[r][c] = fmaf(ar[r], br[c], acc[r][c]);
    }
    __syncthreads();
  }
  const float so = a2 * av[0];
  const float ipa = apa[0];
  int bb = bh / 6, h = bh % 6;
#pragma unroll
  for (int r = 0; r < 4; ++r) {
    int i = i0 + (ty << 2) + r;
#pragma unroll
    for (int c = 0; c < 4; ++c) {
      int d = (tx << 2) + c;
      ows[(size_t)((bb << 11) + i) * 384 + (h << 6) + d] =
          rintf(qclip(acc[r][c] * so / ipa));
    }
  }
}

// ---------------- proj: [4096,384] @ [384,384]^T * s + bias ----------------
__global__ __launch_bounds__(256)
void gemm_proj(const float* __restrict__ A, const float* __restrict__ W,
               const float* __restrict__ bias, float* __restrict__ out,
               const float* __restrict__ apa, const float* __restrict__ apw) {
  __shared__ float As[32][68];
  __shared__ float Bs[32][68];
  const int t = threadIdx.x;
  const int tx = t & 15, ty = t >> 4;
  const int m0 = blockIdx.x * 64, n0 = blockIdx.y * 64;
  float acc[4][4] = {};
  for (int k0 = 0; k0 < 384; k0 += 32) {
#pragma unroll
    for (int u = 0; u < 2; ++u) {
      int s4 = t + u * 256;
      int row = s4 >> 3;
      int col = (s4 & 7) << 2;
      float4 va = *(const float4*)(A + (size_t)(m0 + row) * 384 + k0 + col);
      As[col + 0][row] = va.x; As[col + 1][row] = va.y;
      As[col + 2][row] = va.z; As[col + 3][row] = va.w;
      float4 vb = *(const float4*)(W + (size_t)(n0 + row) * 384 + k0 + col);
      Bs[col + 0][row] = vb.x; Bs[col + 1][row] = vb.y;
      Bs[col + 2][row] = vb.z; Bs[col + 3][row] = vb.w;
    }
    __syncthreads();
#pragma unroll
    for (int kk = 0; kk < 32; ++kk) {
      float4 a4 = *(float4*)(&As[kk][ty << 2]);
      float4 b4 = *(float4*)(&Bs[kk][tx << 2]);
      float ar[4] = {a4.x, a4.y, a4.z, a4.w};
      float br[4] = {b4.x, b4.y, b4.z, b4.w};
#pragma unroll
      for (int r = 0; r < 4; ++r)
#pragma unroll
        for (int c = 0; c < 4; ++c)
          acc[r][c] = fmaf(ar[r], br[c], acc[r][c]);
    }
    __syncthreads();
  }
  const float sAB = apa[0] * apw[0];
#pragma unroll
  for (int r = 0; r < 4; ++r) {
    int m = m0 + (ty << 2) + r;
#pragma unroll
    for (int c = 0; c < 4; ++c) {
      int cg = n0 + (tx << 2) + c;
      out[(size_t)m * 384 + cg] = acc[r][c] * sAB + bias[cg];
    }
  }
}

extern "C" void kernel_launch(void* const* d_in, const int* in_sizes, int n_in,
                              void* d_out, int out_size, void* d_ws, size_t ws_size,
                              hipStream_t stream) {
  const float* x       = (const float*)d_in[0];
  const float* w_qkv   = (const float*)d_in[1];
  const float* w_proj  = (const float*)d_in[2];
  const float* b_proj  = (const float*)d_in[3];
  const float* a_qkv_w = (const float*)d_in[4];
  const float* a_qkv_a = (const float*)d_in[5];
  const float* a_proj_w= (const float*)d_in[6];
  const float* a_proj_a= (const float*)d_in[7];
  const float* a_q     = (const float*)d_in[8];
  const float* a_k     = (const float*)d_in[9];
  const float* a_v     = (const float*)d_in[10];
  const float* a_attn  = (const float*)d_in[11];
  const float* a_attn2 = (const float*)d_in[12];

  char* wsb = (char*)d_ws;
  float*  xq    = (float*)(wsb + 0);          // 4096*384 f32   = 6,291,456 B
  float*  wqq   = (float*)(wsb + 6291456);    // 1152*384 f32   = 1,769,472 B
  float*  wpq   = (float*)(wsb + 8060928);    //  384*384 f32   =   589,824 B
  float*  qws   = (float*)(wsb + 8650752);    // 12*2048*64 f32 = 6,291,456 B
  float*  kws   = (float*)(wsb + 14942208);   // same
  float*  vwsT  = (float*)(wsb + 21233664);   // same (transposed [bh,d,n])
  float*  ows   = (float*)(wsb + 27525120);   // 4096*384 f32   = 6,291,456 B
  float2* stats = (float2*)(wsb + 33816576);  // 24576 float2   =   196,608 B
  signed char* Sq = (signed char*)(wsb + 34013184); // 12*2048*2048 = 50,331,648 B
  // total ws usage: 84,344,832 bytes

  quant4_kernel<<<1536, 256, 0, stream>>>(x, xq, a_qkv_a, 393216);
  quant4_kernel<<<432, 256, 0, stream>>>(w_qkv, wqq, a_qkv_w, 110592);
  quant4_kernel<<<144, 256, 0, stream>>>(w_proj, wpq, a_proj_w, 36864);
  gemm_qkv<<<dim3(64, 18), 256, 0, stream>>>(xq, wqq, qws, kws, vwsT,
                                             a_qkv_a, a_qkv_w, a_q, a_k, a_v);
  gemm_scores<<<dim3(32, 32, 12), 256, 0, stream>>>(qws, kws, Sq, a_q, a_k, a_attn);
  softmax_stats<<<6144, 256, 0, stream>>>(Sq, stats, a_attn);
  gemm_pv<<<dim3(32, 12), 256, 0, stream>>>(Sq, vwsT, stats, ows,
                                            a_attn, a_attn2, a_v, a_proj_a);
  gemm_proj<<<dim3(64, 6), 256, 0, stream>>>(ows, wpq, b_proj, (float*)d_out,
                                             a_proj_a, a_proj_w);
}

// Round 2
// 279.753 us; speedup vs baseline: 1.6726x; 1.6726x over previous
//
#include <hip/hip_runtime.h>
#include <hip/hip_bf16.h>
#include <math.h>

// B=2, N=2048, C=384, H=6, D=64.  All quantized tensors hold INTEGER values
// (round(clip(x/a))) stored as bf16 (exact for |v|<=128); alpha scales are
// factored into epilogues with expressions identical to the verified
// vector-ALU baseline (absmax 0.0).  MFMA fp32 accumulation of these
// integers is exact, so results stay bit-identical.

typedef __bf16 bf16x8 __attribute__((ext_vector_type(8)));
typedef float f32x4 __attribute__((ext_vector_type(4)));

#define MFMA16(a, b, c) __builtin_amdgcn_mfma_f32_16x16x32_bf16(a, b, c, 0, 0, 0)

__device__ __forceinline__ float qclip(float s) {
  return fminf(fmaxf(s, -128.0f), 127.0f);
}

__device__ __forceinline__ unsigned short f2bu(float f) {
  __hip_bfloat16 h = __float2bfloat16(f);
  union { __hip_bfloat16 h; unsigned short u; } cv;
  cv.h = h;
  return cv.u;
}

// ---------------- elementwise quantize -> bf16 ints (8 elems/thread) ----------------
__global__ __launch_bounds__(256)
void quantb8(const float* __restrict__ in, unsigned short* __restrict__ out,
             const float* __restrict__ alpha, int n8) {
  int i = blockIdx.x * 256 + threadIdx.x;
  if (i >= n8) return;
  float a = alpha[0];
  float4 v0 = ((const float4*)in)[2 * i];
  float4 v1 = ((const float4*)in)[2 * i + 1];
  union { uint4 u; unsigned short s[8]; } o;
  o.s[0] = f2bu(rintf(qclip(v0.x / a)));
  o.s[1] = f2bu(rintf(qclip(v0.y / a)));
  o.s[2] = f2bu(rintf(qclip(v0.z / a)));
  o.s[3] = f2bu(rintf(qclip(v0.w / a)));
  o.s[4] = f2bu(rintf(qclip(v1.x / a)));
  o.s[5] = f2bu(rintf(qclip(v1.y / a)));
  o.s[6] = f2bu(rintf(qclip(v1.z / a)));
  o.s[7] = f2bu(rintf(qclip(v1.w / a)));
  *(uint4*)(out + 8 * i) = o.u;
}

// ---------------- QKV GEMM (MFMA): [4096,384] @ [1152,384]^T ----------------
// 128x128 block = 2x2 waves of 64x64.  Epilogue requants to bf16 q,k,vT.
__global__ __launch_bounds__(256)
void gemm_qkv(const unsigned short* __restrict__ A, const unsigned short* __restrict__ W,
              unsigned short* __restrict__ qws, unsigned short* __restrict__ kws,
              unsigned short* __restrict__ vwsT,
              const float* __restrict__ aa, const float* __restrict__ aw,
              const float* __restrict__ aq, const float* __restrict__ ak,
              const float* __restrict__ av) {
  const int t = threadIdx.x;
  const int w = t >> 6, lane = t & 63;
  const int lm = lane & 15, quad = lane >> 4;
  const int wm = w >> 1, wn = w & 1;
  const int m0 = blockIdx.x * 128 + wm * 64;
  const int n0 = blockIdx.y * 128 + wn * 64;
  f32x4 acc[4][4] = {};
  for (int k0 = 0; k0 < 384; k0 += 32) {
    bf16x8 af[4], bf[4];
#pragma unroll
    for (int mt = 0; mt < 4; ++mt)
      af[mt] = *(const bf16x8*)(A + (size_t)(m0 + mt * 16 + lm) * 384 + k0 + quad * 8);
#pragma unroll
    for (int nt = 0; nt < 4; ++nt)
      bf[nt] = *(const bf16x8*)(W + (size_t)(n0 + nt * 16 + lm) * 384 + k0 + quad * 8);
#pragma unroll
    for (int mt = 0; mt < 4; ++mt)
#pragma unroll
      for (int nt = 0; nt < 4; ++nt)
        acc[mt][nt] = MFMA16(af[mt], bf[nt], acc[mt][nt]);
  }
  const float sAB = aa[0] * aw[0];
  const float vaq = aq[0], vak = ak[0], vav = av[0];
#pragma unroll
  for (int mt = 0; mt < 4; ++mt) {
#pragma unroll
    for (int nt = 0; nt < 4; ++nt) {
      int cg = n0 + nt * 16 + lm;
      int t3 = cg / 384;
      int rem = cg - t3 * 384;
      int h = rem >> 6, d = rem & 63;
#pragma unroll
      for (int r = 0; r < 4; ++r) {
        int m = m0 + mt * 16 + quad * 4 + r;
        int bb = m >> 11, nn = m & 2047;
        int bh = bb * 6 + h;
        float val = acc[mt][nt][r] * sAB;
        if (t3 == 0) {
          qws[((size_t)(bh * 2048 + nn) << 6) + d] = f2bu(rintf(qclip(val / vaq)));
        } else if (t3 == 1) {
          kws[((size_t)(bh * 2048 + nn) << 6) + d] = f2bu(rintf(qclip(val / vak)));
        } else {
          vwsT[((size_t)((bh << 6) + d) << 11) + nn] = f2bu(rintf(qclip(val / vav)));
        }
      }
    }
  }
}

// ---------------- scores (MFMA): S = q @ k^T, requant -> int8 ----------------
__global__ __launch_bounds__(256)
void gemm_scores(const unsigned short* __restrict__ qws, const unsigned short* __restrict__ kws,
                 signed char* __restrict__ Sq,
                 const float* __restrict__ aq, const float* __restrict__ ak,
                 const float* __restrict__ aattn) {
  const int t = threadIdx.x;
  const int w = t >> 6, lane = t & 63;
  const int lm = lane & 15, quad = lane >> 4;
  const int wm = w >> 1, wn = w & 1;
  const int m0 = blockIdx.x * 128 + wm * 64;
  const int n0 = blockIdx.y * 128 + wn * 64;
  const int bh = blockIdx.z;
  const unsigned short* Aq = qws + ((size_t)bh << 17);
  const unsigned short* Bk = kws + ((size_t)bh << 17);
  f32x4 acc[4][4] = {};
#pragma unroll
  for (int ks = 0; ks < 2; ++ks) {
    bf16x8 af[4], bf[4];
#pragma unroll
    for (int mt = 0; mt < 4; ++mt)
      af[mt] = *(const bf16x8*)(Aq + ((size_t)(m0 + mt * 16 + lm) << 6) + ks * 32 + quad * 8);
#pragma unroll
    for (int nt = 0; nt < 4; ++nt)
      bf[nt] = *(const bf16x8*)(Bk + ((size_t)(n0 + nt * 16 + lm) << 6) + ks * 32 + quad * 8);
#pragma unroll
    for (int mt = 0; mt < 4; ++mt)
#pragma unroll
      for (int nt = 0; nt < 4; ++nt)
        acc[mt][nt] = MFMA16(af[mt], bf[nt], acc[mt][nt]);
  }
  const float sc = aq[0] * ak[0] * 0.125f;
  const float ia = aattn[0];
  signed char* Sb = Sq + ((size_t)bh << 22);
#pragma unroll
  for (int mt = 0; mt < 4; ++mt) {
#pragma unroll
    for (int nt = 0; nt < 4; ++nt) {
      int col = n0 + nt * 16 + lm;
#pragma unroll
      for (int r = 0; r < 4; ++r) {
        int row = m0 + mt * 16 + quad * 4 + r;
        float sv = acc[mt][nt][r] * sc;
        Sb[((size_t)row << 11) + col] = (signed char)(int)rintf(qclip(sv / ia));
      }
    }
  }
}

// ---------------- per-row softmax stats: m = a*max, l = sum exp ----------------
__global__ __launch_bounds__(256)
void softmax_stats(const signed char* __restrict__ Sq, float2* __restrict__ stats,
                   const float* __restrict__ aattn) {
  const int lane = threadIdx.x & 63;
  const int row = (blockIdx.x << 2) + (threadIdx.x >> 6);
  const signed char* p = Sq + ((size_t)row << 11);
  char4 vals[8];
  int vmax = -129;
#pragma unroll
  for (int u = 0; u < 8; ++u) {
    vals[u] = ((const char4*)p)[lane + (u << 6)];
    vmax = max(vmax, (int)vals[u].x);
    vmax = max(vmax, (int)vals[u].y);
    vmax = max(vmax, (int)vals[u].z);
    vmax = max(vmax, (int)vals[u].w);
  }
#pragma unroll
  for (int off = 32; off > 0; off >>= 1)
    vmax = max(vmax, __shfl_xor(vmax, off, 64));
  const float a = aattn[0];
  const float m = a * (float)vmax;
  float l = 0.0f;
#pragma unroll
  for (int u = 0; u < 8; ++u) {
    l += expf(a * (float)vals[u].x - m);
    l += expf(a * (float)vals[u].y - m);
    l += expf(a * (float)vals[u].z - m);
    l += expf(a * (float)vals[u].w - m);
  }
#pragma unroll
  for (int off = 32; off > 0; off >>= 1)
    l += __shfl_xor(l, off, 64);
  if (lane == 0) stats[row] = make_float2(m, l);
}

// ---------------- PV (MFMA): P (on-the-fly from Sq+stats) @ vT^T ----------------
// 128 threads = 2 waves; wave owns 16 output rows, full D=64, K=2048.
__global__ __launch_bounds__(128)
void gemm_pv(const signed char* __restrict__ Sq, const unsigned short* __restrict__ vwsT,
             const float2* __restrict__ stats, unsigned short* __restrict__ ows,
             const float* __restrict__ aattn, const float* __restrict__ aattn2,
             const float* __restrict__ av, const float* __restrict__ apa) {
  const int t = threadIdx.x;
  const int w = t >> 6, lane = t & 63;
  const int lm = lane & 15, quad = lane >> 4;
  const int i0 = blockIdx.x * 32;
  const int bh = blockIdx.y;
  const int arow = i0 + w * 16 + lm;
  const float2 ml = stats[(bh << 11) + arow];
  const float a = aattn[0];
  const float a2 = aattn2[0];
  const signed char* Sb = Sq + ((size_t)bh << 22) + ((size_t)arow << 11) + quad * 8;
  const unsigned short* Vb = vwsT + ((size_t)bh << 17);
  f32x4 acc[4] = {};
  for (int j0 = 0; j0 < 2048; j0 += 32) {
    union { uint2 u; signed char c[8]; } sv;
    sv.u = *(const uint2*)(Sb + j0);
    union { bf16x8 v; unsigned short s[8]; } af;
#pragma unroll
    for (int j = 0; j < 8; ++j) {
      float p = rintf(qclip(expf(a * (float)sv.c[j] - ml.x) / ml.y / a2));
      af.s[j] = f2bu(p);
    }
    bf16x8 bf[4];
#pragma unroll
    for (int nt = 0; nt < 4; ++nt)
      bf[nt] = *(const bf16x8*)(Vb + ((size_t)(nt * 16 + lm) << 11) + j0 + quad * 8);
#pragma unroll
    for (int nt = 0; nt < 4; ++nt)
      acc[nt] = MFMA16(af.v, bf[nt], acc[nt]);
  }
  const float so = a2 * av[0];
  const float ipa = apa[0];
  int bb = bh / 6, h = bh % 6;
#pragma unroll
  for (int nt = 0; nt < 4; ++nt) {
    int d = nt * 16 + lm;
#pragma unroll
    for (int r = 0; r < 4; ++r) {
      int i = i0 + w * 16 + quad * 4 + r;
      ows[(size_t)((bb << 11) + i) * 384 + (h << 6) + d] =
          f2bu(rintf(qclip(acc[nt][r] * so / ipa)));
    }
  }
}

// ---------------- proj (MFMA): [4096,384] @ [384,384]^T * s + bias ----------------
// 64x64 block = 2x2 waves of 32x32.
__global__ __launch_bounds__(256)
void gemm_proj(const unsigned short* __restrict__ A, const unsigned short* __restrict__ W,
               const float* __restrict__ bias, float* __restrict__ out,
               const float* __restrict__ apa, const float* __restrict__ apw) {
  const int t = threadIdx.x;
  const int w = t >> 6, lane = t & 63;
  const int lm = lane & 15, quad = lane >> 4;
  const int wm = w >> 1, wn = w & 1;
  const int m0 = blockIdx.x * 64 + wm * 32;
  const int n0 = blockIdx.y * 64 + wn * 32;
  f32x4 acc[2][2] = {};
  for (int k0 = 0; k0 < 384; k0 += 32) {
    bf16x8 af[2], bf[2];
#pragma unroll
    for (int mt = 0; mt < 2; ++mt)
      af[mt] = *(const bf16x8*)(A + (size_t)(m0 + mt * 16 + lm) * 384 + k0 + quad * 8);
#pragma unroll
    for (int nt = 0; nt < 2; ++nt)
      bf[nt] = *(const bf16x8*)(W + (size_t)(n0 + nt * 16 + lm) * 384 + k0 + quad * 8);
#pragma unroll
    for (int mt = 0; mt < 2; ++mt)
#pragma unroll
      for (int nt = 0; nt < 2; ++nt)
        acc[mt][nt] = MFMA16(af[mt], bf[nt], acc[mt][nt]);
  }
  const float sAB = apa[0] * apw[0];
#pragma unroll
  for (int mt = 0; mt < 2; ++mt) {
#pragma unroll
    for (int nt = 0; nt < 2; ++nt) {
      int cg = n0 + nt * 16 + lm;
#pragma unroll
      for (int r = 0; r < 4; ++r) {
        int m = m0 + mt * 16 + quad * 4 + r;
        out[(size_t)m * 384 + cg] = acc[mt][nt][r] * sAB + bias[cg];
      }
    }
  }
}

extern "C" void kernel_launch(void* const* d_in, const int* in_sizes, int n_in,
                              void* d_out, int out_size, void* d_ws, size_t ws_size,
                              hipStream_t stream) {
  const float* x        = (const float*)d_in[0];
  const float* w_qkv    = (const float*)d_in[1];
  const float* w_proj   = (const float*)d_in[2];
  const float* b_proj   = (const float*)d_in[3];
  const float* a_qkv_w  = (const float*)d_in[4];
  const float* a_qkv_a  = (const float*)d_in[5];
  const float* a_proj_w = (const float*)d_in[6];
  const float* a_proj_a = (const float*)d_in[7];
  const float* a_q      = (const float*)d_in[8];
  const float* a_k      = (const float*)d_in[9];
  const float* a_v      = (const float*)d_in[10];
  const float* a_attn   = (const float*)d_in[11];
  const float* a_attn2  = (const float*)d_in[12];

  char* wsb = (char*)d_ws;
  unsigned short* xq   = (unsigned short*)(wsb + 0);         // 4096*384 bf16  = 3,145,728 B
  unsigned short* wqq  = (unsigned short*)(wsb + 3145728);   // 1152*384 bf16  =   884,736 B
  unsigned short* wpq  = (unsigned short*)(wsb + 4030464);   //  384*384 bf16  =   294,912 B
  unsigned short* qws  = (unsigned short*)(wsb + 4325376);   // 12*2048*64 bf16= 3,145,728 B
  unsigned short* kws  = (unsigned short*)(wsb + 7471104);   // same
  unsigned short* vwsT = (unsigned short*)(wsb + 10616832);  // same, [bh,d,n]
  unsigned short* ows  = (unsigned short*)(wsb + 13762560);  // 4096*384 bf16  = 3,145,728 B
  float2* stats        = (float2*)(wsb + 16908288);          // 24576 float2   =   196,608 B
  signed char* Sq      = (signed char*)(wsb + 17104896);     // 12*2048*2048   = 50,331,648 B
  // total ws usage: 67,436,544 bytes

  quantb8<<<768, 256, 0, stream>>>(x, xq, a_qkv_a, 196608);
  quantb8<<<216, 256, 0, stream>>>(w_qkv, wqq, a_qkv_w, 55296);
  quantb8<<<72, 256, 0, stream>>>(w_proj, wpq, a_proj_w, 18432);
  gemm_qkv<<<dim3(32, 9), 256, 0, stream>>>(xq, wqq, qws, kws, vwsT,
                                            a_qkv_a, a_qkv_w, a_q, a_k, a_v);
  gemm_scores<<<dim3(16, 16, 12), 256, 0, stream>>>(qws, kws, Sq, a_q, a_k, a_attn);
  softmax_stats<<<6144, 256, 0, stream>>>(Sq, stats, a_attn);
  gemm_pv<<<dim3(64, 12), 128, 0, stream>>>(Sq, vwsT, stats, ows,
                                            a_attn, a_attn2, a_v, a_proj_a);
  gemm_proj<<<dim3(64, 6), 256, 0, stream>>>(ows, wpq, b_proj, (float*)d_out,
                                             a_proj_a, a_proj_w);
}

// Round 3
// 252.159 us; speedup vs baseline: 1.8556x; 1.1094x over previous
//
#include <hip/hip_runtime.h>
#include <hip/hip_bf16.h>
#include <math.h>

// B=2, N=2048, C=384, H=6, D=64.  All quantized tensors hold INTEGER values
// (round(clip(x/a))) stored as bf16 (exact for |v|<=128); alpha scales are
// factored into epilogues with expressions identical to the verified
// vector-ALU baseline (absmax 0.0).  MFMA fp32 accumulation of these
// integers is exact, so results stay bit-identical.
//
// Round 3: softmax requant collapsed to a per-row 256-entry bf16 LUT
// (built in softmax_lut with the exact same fp32 expression), and gemm_pv
// K-split across 2 waves per block (LDS reduce, exact integer sums).

typedef __bf16 bf16x8 __attribute__((ext_vector_type(8)));
typedef float f32x4 __attribute__((ext_vector_type(4)));

#define MFMA16(a, b, c) __builtin_amdgcn_mfma_f32_16x16x32_bf16(a, b, c, 0, 0, 0)

__device__ __forceinline__ float qclip(float s) {
  return fminf(fmaxf(s, -128.0f), 127.0f);
}

__device__ __forceinline__ unsigned short f2bu(float f) {
  __hip_bfloat16 h = __float2bfloat16(f);
  union { __hip_bfloat16 h; unsigned short u; } cv;
  cv.h = h;
  return cv.u;
}

// ---------------- elementwise quantize -> bf16 ints (8 elems/thread) ----------------
__global__ __launch_bounds__(256)
void quantb8(const float* __restrict__ in, unsigned short* __restrict__ out,
             const float* __restrict__ alpha, int n8) {
  int i = blockIdx.x * 256 + threadIdx.x;
  if (i >= n8) return;
  float a = alpha[0];
  float4 v0 = ((const float4*)in)[2 * i];
  float4 v1 = ((const float4*)in)[2 * i + 1];
  union { uint4 u; unsigned short s[8]; } o;
  o.s[0] = f2bu(rintf(qclip(v0.x / a)));
  o.s[1] = f2bu(rintf(qclip(v0.y / a)));
  o.s[2] = f2bu(rintf(qclip(v0.z / a)));
  o.s[3] = f2bu(rintf(qclip(v0.w / a)));
  o.s[4] = f2bu(rintf(qclip(v1.x / a)));
  o.s[5] = f2bu(rintf(qclip(v1.y / a)));
  o.s[6] = f2bu(rintf(qclip(v1.z / a)));
  o.s[7] = f2bu(rintf(qclip(v1.w / a)));
  *(uint4*)(out + 8 * i) = o.u;
}

// ---------------- QKV GEMM (MFMA): [4096,384] @ [1152,384]^T ----------------
__global__ __launch_bounds__(256)
void gemm_qkv(const unsigned short* __restrict__ A, const unsigned short* __restrict__ W,
              unsigned short* __restrict__ qws, unsigned short* __restrict__ kws,
              unsigned short* __restrict__ vwsT,
              const float* __restrict__ aa, const float* __restrict__ aw,
              const float* __restrict__ aq, const float* __restrict__ ak,
              const float* __restrict__ av) {
  const int t = threadIdx.x;
  const int w = t >> 6, lane = t & 63;
  const int lm = lane & 15, quad = lane >> 4;
  const int wm = w >> 1, wn = w & 1;
  const int m0 = blockIdx.x * 128 + wm * 64;
  const int n0 = blockIdx.y * 128 + wn * 64;
  f32x4 acc[4][4] = {};
  for (int k0 = 0; k0 < 384; k0 += 32) {
    bf16x8 af[4], bf[4];
#pragma unroll
    for (int mt = 0; mt < 4; ++mt)
      af[mt] = *(const bf16x8*)(A + (size_t)(m0 + mt * 16 + lm) * 384 + k0 + quad * 8);
#pragma unroll
    for (int nt = 0; nt < 4; ++nt)
      bf[nt] = *(const bf16x8*)(W + (size_t)(n0 + nt * 16 + lm) * 384 + k0 + quad * 8);
#pragma unroll
    for (int mt = 0; mt < 4; ++mt)
#pragma unroll
      for (int nt = 0; nt < 4; ++nt)
        acc[mt][nt] = MFMA16(af[mt], bf[nt], acc[mt][nt]);
  }
  const float sAB = aa[0] * aw[0];
  const float vaq = aq[0], vak = ak[0], vav = av[0];
#pragma unroll
  for (int mt = 0; mt < 4; ++mt) {
#pragma unroll
    for (int nt = 0; nt < 4; ++nt) {
      int cg = n0 + nt * 16 + lm;
      int t3 = cg / 384;
      int rem = cg - t3 * 384;
      int h = rem >> 6, d = rem & 63;
#pragma unroll
      for (int r = 0; r < 4; ++r) {
        int m = m0 + mt * 16 + quad * 4 + r;
        int bb = m >> 11, nn = m & 2047;
        int bh = bb * 6 + h;
        float val = acc[mt][nt][r] * sAB;
        if (t3 == 0) {
          qws[((size_t)(bh * 2048 + nn) << 6) + d] = f2bu(rintf(qclip(val / vaq)));
        } else if (t3 == 1) {
          kws[((size_t)(bh * 2048 + nn) << 6) + d] = f2bu(rintf(qclip(val / vak)));
        } else {
          vwsT[((size_t)((bh << 6) + d) << 11) + nn] = f2bu(rintf(qclip(val / vav)));
        }
      }
    }
  }
}

// ---------------- scores (MFMA): S = q @ k^T, requant -> int8 ----------------
__global__ __launch_bounds__(256)
void gemm_scores(const unsigned short* __restrict__ qws, const unsigned short* __restrict__ kws,
                 signed char* __restrict__ Sq,
                 const float* __restrict__ aq, const float* __restrict__ ak,
                 const float* __restrict__ aattn) {
  const int t = threadIdx.x;
  const int w = t >> 6, lane = t & 63;
  const int lm = lane & 15, quad = lane >> 4;
  const int wm = w >> 1, wn = w & 1;
  const int m0 = blockIdx.x * 128 + wm * 64;
  const int n0 = blockIdx.y * 128 + wn * 64;
  const int bh = blockIdx.z;
  const unsigned short* Aq = qws + ((size_t)bh << 17);
  const unsigned short* Bk = kws + ((size_t)bh << 17);
  f32x4 acc[4][4] = {};
#pragma unroll
  for (int ks = 0; ks < 2; ++ks) {
    bf16x8 af[4], bf[4];
#pragma unroll
    for (int mt = 0; mt < 4; ++mt)
      af[mt] = *(const bf16x8*)(Aq + ((size_t)(m0 + mt * 16 + lm) << 6) + ks * 32 + quad * 8);
#pragma unroll
    for (int nt = 0; nt < 4; ++nt)
      bf[nt] = *(const bf16x8*)(Bk + ((size_t)(n0 + nt * 16 + lm) << 6) + ks * 32 + quad * 8);
#pragma unroll
    for (int mt = 0; mt < 4; ++mt)
#pragma unroll
      for (int nt = 0; nt < 4; ++nt)
        acc[mt][nt] = MFMA16(af[mt], bf[nt], acc[mt][nt]);
  }
  const float sc = aq[0] * ak[0] * 0.125f;
  const float ia = aattn[0];
  signed char* Sb = Sq + ((size_t)bh << 22);
#pragma unroll
  for (int mt = 0; mt < 4; ++mt) {
#pragma unroll
    for (int nt = 0; nt < 4; ++nt) {
      int col = n0 + nt * 16 + lm;
#pragma unroll
      for (int r = 0; r < 4; ++r) {
        int row = m0 + mt * 16 + quad * 4 + r;
        float sv = acc[mt][nt][r] * sc;
        Sb[((size_t)row << 11) + col] = (signed char)(int)rintf(qclip(sv / ia));
      }
    }
  }
}

// ---------------- per-row softmax LUT: lut[row][s+128] = quantized P(s) ----------------
__global__ __launch_bounds__(256)
void softmax_lut(const signed char* __restrict__ Sq, unsigned short* __restrict__ lut,
                 const float* __restrict__ aattn, const float* __restrict__ aattn2) {
  const int lane = threadIdx.x & 63;
  const int row = (blockIdx.x << 2) + (threadIdx.x >> 6);
  const signed char* p = Sq + ((size_t)row << 11);
  char4 vals[8];
  int vmax = -129;
#pragma unroll
  for (int u = 0; u < 8; ++u) {
    vals[u] = ((const char4*)p)[lane + (u << 6)];
    vmax = max(vmax, (int)vals[u].x);
    vmax = max(vmax, (int)vals[u].y);
    vmax = max(vmax, (int)vals[u].z);
    vmax = max(vmax, (int)vals[u].w);
  }
#pragma unroll
  for (int off = 32; off > 0; off >>= 1)
    vmax = max(vmax, __shfl_xor(vmax, off, 64));
  const float a = aattn[0];
  const float m = a * (float)vmax;
  float l = 0.0f;
#pragma unroll
  for (int u = 0; u < 8; ++u) {
    l += expf(a * (float)vals[u].x - m);
    l += expf(a * (float)vals[u].y - m);
    l += expf(a * (float)vals[u].z - m);
    l += expf(a * (float)vals[u].w - m);
  }
#pragma unroll
  for (int off = 32; off > 0; off >>= 1)
    l += __shfl_xor(l, off, 64);
  // all lanes now hold the full row max and sum; emit the 256-entry LUT
  const float a2 = aattn2[0];
  unsigned short* lr = lut + ((size_t)row << 8);
#pragma unroll
  for (int u = 0; u < 4; ++u) {
    int s = u * 64 + lane - 128;
    float arg;
    {
#pragma clang fp contract(off)
      arg = a * (float)s - m;   // mul-then-sub, matching the softmax path
    }
    float pq = expf(arg) / l / a2;
    lr[u * 64 + lane] = f2bu(rintf(qclip(pq)));
  }
}

// ---------------- PV (MFMA): P (LUT lookup from Sq) @ vT^T ----------------
// Block = 128 thr = 2 waves over the SAME 16 rows; wave w sums K-half
// [w*1024,(w+1)*1024); exact integer partial sums reduced through LDS.
__global__ __launch_bounds__(128)
void gemm_pv(const signed char* __restrict__ Sq, const unsigned short* __restrict__ vwsT,
             const unsigned short* __restrict__ lut, unsigned short* __restrict__ ows,
             const float* __restrict__ aattn2, const float* __restrict__ av,
             const float* __restrict__ apa) {
  __shared__ unsigned short lutS[16 * 264];  // row stride 264 spreads banks
  __shared__ float red[64 * 17];
  const int t = threadIdx.x;
  const int w = t >> 6, lane = t & 63;
  const int lm = lane & 15, quad = lane >> 4;
  const int i0 = blockIdx.x * 16;
  const int bh = blockIdx.y;
  // stage this block's 16 LUT rows into LDS
  {
    int r = t >> 3, seg = t & 7;
    const uint4* src = (const uint4*)(lut + ((((size_t)bh << 11) + i0 + r) << 8) + seg * 32);
    uint4* dst = (uint4*)(lutS + r * 264 + seg * 32);
#pragma unroll
    for (int u = 0; u < 4; ++u) dst[u] = src[u];
  }
  __syncthreads();
  const int arow = i0 + lm;
  const signed char* Sb = Sq + ((size_t)bh << 22) + ((size_t)arow << 11) + (w << 10) + quad * 8;
  const unsigned short* Vb = vwsT + ((size_t)bh << 17) + (w << 10);
  const unsigned short* lrow = lutS + lm * 264 + 128;
  f32x4 acc[4] = {};
  for (int j0 = 0; j0 < 1024; j0 += 32) {
    union { uint2 u; signed char c[8]; } sv;
    sv.u = *(const uint2*)(Sb + j0);
    union { bf16x8 v; unsigned short s[8]; } af;
#pragma unroll
    for (int j = 0; j < 8; ++j) af.s[j] = lrow[(int)sv.c[j]];
    bf16x8 bf[4];
#pragma unroll
    for (int nt = 0; nt < 4; ++nt)
      bf[nt] = *(const bf16x8*)(Vb + ((size_t)(nt * 16 + lm) << 11) + j0 + quad * 8);
#pragma unroll
    for (int nt = 0; nt < 4; ++nt)
      acc[nt] = MFMA16(af.v, bf[nt], acc[nt]);
  }
  if (w == 1) {
#pragma unroll
    for (int nt = 0; nt < 4; ++nt)
#pragma unroll
      for (int r = 0; r < 4; ++r)
        red[lane * 17 + nt * 4 + r] = acc[nt][r];
  }
  __syncthreads();
  if (w == 0) {
    const float so = aattn2[0] * av[0];
    const float ipa = apa[0];
    int bb = bh / 6, h = bh % 6;
#pragma unroll
    for (int nt = 0; nt < 4; ++nt) {
      int d = nt * 16 + lm;
#pragma unroll
      for (int r = 0; r < 4; ++r) {
        float s = acc[nt][r] + red[lane * 17 + nt * 4 + r];
        int i = i0 + quad * 4 + r;
        ows[(size_t)((bb << 11) + i) * 384 + (h << 6) + d] =
            f2bu(rintf(qclip(s * so / ipa)));
      }
    }
  }
}

// ---------------- proj (MFMA): [4096,384] @ [384,384]^T * s + bias ----------------
__global__ __launch_bounds__(256)
void gemm_proj(const unsigned short* __restrict__ A, const unsigned short* __restrict__ W,
               const float* __restrict__ bias, float* __restrict__ out,
               const float* __restrict__ apa, const float* __restrict__ apw) {
  const int t = threadIdx.x;
  const int w = t >> 6, lane = t & 63;
  const int lm = lane & 15, quad = lane >> 4;
  const int wm = w >> 1, wn = w & 1;
  const int m0 = blockIdx.x * 64 + wm * 32;
  const int n0 = blockIdx.y * 64 + wn * 32;
  f32x4 acc[2][2] = {};
  for (int k0 = 0; k0 < 384; k0 += 32) {
    bf16x8 af[2], bf[2];
#pragma unroll
    for (int mt = 0; mt < 2; ++mt)
      af[mt] = *(const bf16x8*)(A + (size_t)(m0 + mt * 16 + lm) * 384 + k0 + quad * 8);
#pragma unroll
    for (int nt = 0; nt < 2; ++nt)
      bf[nt] = *(const bf16x8*)(W + (size_t)(n0 + nt * 16 + lm) * 384 + k0 + quad * 8);
#pragma unroll
    for (int mt = 0; mt < 2; ++mt)
#pragma unroll
      for (int nt = 0; nt < 2; ++nt)
        acc[mt][nt] = MFMA16(af[mt], bf[nt], acc[mt][nt]);
  }
  const float sAB = apa[0] * apw[0];
#pragma unroll
  for (int mt = 0; mt < 2; ++mt) {
#pragma unroll
    for (int nt = 0; nt < 2; ++nt) {
      int cg = n0 + nt * 16 + lm;
#pragma unroll
      for (int r = 0; r < 4; ++r) {
        int m = m0 + mt * 16 + quad * 4 + r;
        out[(size_t)m * 384 + cg] = acc[mt][nt][r] * sAB + bias[cg];
      }
    }
  }
}

extern "C" void kernel_launch(void* const* d_in, const int* in_sizes, int n_in,
                              void* d_out, int out_size, void* d_ws, size_t ws_size,
                              hipStream_t stream) {
  const float* x        = (const float*)d_in[0];
  const float* w_qkv    = (const float*)d_in[1];
  const float* w_proj   = (const float*)d_in[2];
  const float* b_proj   = (const float*)d_in[3];
  const float* a_qkv_w  = (const float*)d_in[4];
  const float* a_qkv_a  = (const float*)d_in[5];
  const float* a_proj_w = (const float*)d_in[6];
  const float* a_proj_a = (const float*)d_in[7];
  const float* a_q      = (const float*)d_in[8];
  const float* a_k      = (const float*)d_in[9];
  const float* a_v      = (const float*)d_in[10];
  const float* a_attn   = (const float*)d_in[11];
  const float* a_attn2  = (const float*)d_in[12];

  char* wsb = (char*)d_ws;
  unsigned short* xq   = (unsigned short*)(wsb + 0);         // 3,145,728 B
  unsigned short* wqq  = (unsigned short*)(wsb + 3145728);   //   884,736 B
  unsigned short* wpq  = (unsigned short*)(wsb + 4030464);   //   294,912 B
  unsigned short* qws  = (unsigned short*)(wsb + 4325376);   // 3,145,728 B
  unsigned short* kws  = (unsigned short*)(wsb + 7471104);   // 3,145,728 B
  unsigned short* vwsT = (unsigned short*)(wsb + 10616832);  // 3,145,728 B  [bh,d,n]
  unsigned short* ows  = (unsigned short*)(wsb + 13762560);  // 3,145,728 B
  unsigned short* lut  = (unsigned short*)(wsb + 16908288);  // 24576*256*2 = 12,582,912 B
  signed char* Sq      = (signed char*)(wsb + 29491200);     // 50,331,648 B
  // total ws usage: 79,822,848 bytes

  quantb8<<<768, 256, 0, stream>>>(x, xq, a_qkv_a, 196608);
  quantb8<<<216, 256, 0, stream>>>(w_qkv, wqq, a_qkv_w, 55296);
  quantb8<<<72, 256, 0, stream>>>(w_proj, wpq, a_proj_w, 18432);
  gemm_qkv<<<dim3(32, 9), 256, 0, stream>>>(xq, wqq, qws, kws, vwsT,
                                            a_qkv_a, a_qkv_w, a_q, a_k, a_v);
  gemm_scores<<<dim3(16, 16, 12), 256, 0, stream>>>(qws, kws, Sq, a_q, a_k, a_attn);
  softmax_lut<<<6144, 256, 0, stream>>>(Sq, lut, a_attn, a_attn2);
  gemm_pv<<<dim3(128, 12), 128, 0, stream>>>(Sq, vwsT, lut, ows,
                                             a_attn2, a_v, a_proj_a);
  gemm_proj<<<dim3(64, 6), 256, 0, stream>>>(ows, wpq, b_proj, (float*)d_out,
                                             a_proj_a, a_proj_w);
}

// Round 4
// 211.149 us; speedup vs baseline: 2.2160x; 1.1942x over previous
//
#include <hip/hip_runtime.h>
#include <hip/hip_bf16.h>
#include <math.h>

// B=2, N=2048, C=384, H=6, D=64.  All quantized tensors hold INTEGER values
// (round(clip(x/a))) stored as int8; alpha scales are factored into epilogues
// with expressions identical to the verified baseline (absmax 0.0).
// All GEMMs use v_mfma_i32_16x16x64_i8: i32 accumulation is exact, and every
// final sum is < 2^24, so the (float) conversion in the epilogue reproduces
// the f32-accumulated value bit-exactly.
//
// Round 4: int8 everywhere; softmax applies its per-row LUT itself and
// rewrites Sq -> Pq in place; gemm_pv is a pure streaming int8 GEMM with
// 4-way K-split (exact integer LDS reduce).

typedef int i32x4 __attribute__((ext_vector_type(4)));

#define MFMA_I8(a, b, c) __builtin_amdgcn_mfma_i32_16x16x64_i8(a, b, c, 0, 0, 0)

__device__ __forceinline__ float qclip(float s) {
  return fminf(fmaxf(s, -128.0f), 127.0f);
}

// ---------------- elementwise quantize -> int8 (16 elems/thread) ----------------
__global__ __launch_bounds__(256)
void quant16(const float* __restrict__ in, signed char* __restrict__ out,
             const float* __restrict__ alpha, int n16) {
  int i = blockIdx.x * 256 + threadIdx.x;
  if (i >= n16) return;
  float a = alpha[0];
  const float4* p = (const float4*)in + 4 * (size_t)i;
  union { uint4 u; signed char c[16]; } o;
#pragma unroll
  for (int u = 0; u < 4; ++u) {
    float4 v = p[u];
    o.c[4 * u + 0] = (signed char)(int)rintf(qclip(v.x / a));
    o.c[4 * u + 1] = (signed char)(int)rintf(qclip(v.y / a));
    o.c[4 * u + 2] = (signed char)(int)rintf(qclip(v.z / a));
    o.c[4 * u + 3] = (signed char)(int)rintf(qclip(v.w / a));
  }
  *(uint4*)(out + 16 * (size_t)i) = o.u;
}

// ---------------- QKV GEMM (i8 MFMA): [4096,384] @ [1152,384]^T ----------------
// 128x128 block = 2x2 waves of 64x64.  Epilogue requants to int8 q,k,vT.
__global__ __launch_bounds__(256)
void gemm_qkv(const signed char* __restrict__ A, const signed char* __restrict__ W,
              signed char* __restrict__ qws, signed char* __restrict__ kws,
              signed char* __restrict__ vwsT,
              const float* __restrict__ aa, const float* __restrict__ aw,
              const float* __restrict__ aq, const float* __restrict__ ak,
              const float* __restrict__ av) {
  const int t = threadIdx.x;
  const int w = t >> 6, lane = t & 63;
  const int lm = lane & 15, quad = lane >> 4;
  const int wm = w >> 1, wn = w & 1;
  const int m0 = blockIdx.x * 128 + wm * 64;
  const int n0 = blockIdx.y * 128 + wn * 64;
  i32x4 acc[4][4] = {};
  for (int k0 = 0; k0 < 384; k0 += 64) {
    i32x4 af[4], bf[4];
#pragma unroll
    for (int mt = 0; mt < 4; ++mt)
      af[mt] = *(const i32x4*)(A + (size_t)(m0 + mt * 16 + lm) * 384 + k0 + quad * 16);
#pragma unroll
    for (int nt = 0; nt < 4; ++nt)
      bf[nt] = *(const i32x4*)(W + (size_t)(n0 + nt * 16 + lm) * 384 + k0 + quad * 16);
#pragma unroll
    for (int mt = 0; mt < 4; ++mt)
#pragma unroll
      for (int nt = 0; nt < 4; ++nt)
        acc[mt][nt] = MFMA_I8(af[mt], bf[nt], acc[mt][nt]);
  }
  const float sAB = aa[0] * aw[0];
  const float vaq = aq[0], vak = ak[0], vav = av[0];
#pragma unroll
  for (int mt = 0; mt < 4; ++mt) {
#pragma unroll
    for (int nt = 0; nt < 4; ++nt) {
      int cg = n0 + nt * 16 + lm;
      int t3 = cg / 384;
      int rem = cg - t3 * 384;
      int h = rem >> 6, d = rem & 63;
#pragma unroll
      for (int r = 0; r < 4; ++r) {
        int m = m0 + mt * 16 + quad * 4 + r;
        int bb = m >> 11, nn = m & 2047;
        int bh = bb * 6 + h;
        float val = (float)acc[mt][nt][r] * sAB;
        if (t3 == 0) {
          qws[((size_t)(bh * 2048 + nn) << 6) + d] = (signed char)(int)rintf(qclip(val / vaq));
        } else if (t3 == 1) {
          kws[((size_t)(bh * 2048 + nn) << 6) + d] = (signed char)(int)rintf(qclip(val / vak));
        } else {
          vwsT[((size_t)((bh << 6) + d) << 11) + nn] = (signed char)(int)rintf(qclip(val / vav));
        }
      }
    }
  }
}

// ---------------- scores (i8 MFMA): S = q @ k^T, requant -> int8 ----------------
// K=64 in a single MFMA per 16x16 tile.
__global__ __launch_bounds__(256)
void gemm_scores(const signed char* __restrict__ qws, const signed char* __restrict__ kws,
                 signed char* __restrict__ Sq,
                 const float* __restrict__ aq, const float* __restrict__ ak,
                 const float* __restrict__ aattn) {
  const int t = threadIdx.x;
  const int w = t >> 6, lane = t & 63;
  const int lm = lane & 15, quad = lane >> 4;
  const int wm = w >> 1, wn = w & 1;
  const int m0 = blockIdx.x * 128 + wm * 64;
  const int n0 = blockIdx.y * 128 + wn * 64;
  const int bh = blockIdx.z;
  const signed char* Aq = qws + ((size_t)bh << 17);
  const signed char* Bk = kws + ((size_t)bh << 17);
  i32x4 acc[4][4] = {};
  i32x4 af[4], bf[4];
#pragma unroll
  for (int mt = 0; mt < 4; ++mt)
    af[mt] = *(const i32x4*)(Aq + ((size_t)(m0 + mt * 16 + lm) << 6) + quad * 16);
#pragma unroll
  for (int nt = 0; nt < 4; ++nt)
    bf[nt] = *(const i32x4*)(Bk + ((size_t)(n0 + nt * 16 + lm) << 6) + quad * 16);
#pragma unroll
  for (int mt = 0; mt < 4; ++mt)
#pragma unroll
    for (int nt = 0; nt < 4; ++nt)
      acc[mt][nt] = MFMA_I8(af[mt], bf[nt], acc[mt][nt]);
  const float sc = aq[0] * ak[0] * 0.125f;
  const float ia = aattn[0];
  signed char* Sb = Sq + ((size_t)bh << 22);
#pragma unroll
  for (int mt = 0; mt < 4; ++mt) {
#pragma unroll
    for (int nt = 0; nt < 4; ++nt) {
      int col = n0 + nt * 16 + lm;
#pragma unroll
      for (int r = 0; r < 4; ++r) {
        int row = m0 + mt * 16 + quad * 4 + r;
        float sv = (float)acc[mt][nt][r] * sc;
        Sb[((size_t)row << 11) + col] = (signed char)(int)rintf(qclip(sv / ia));
      }
    }
  }
}

// ---------------- softmax + requant, in place: Sq -> Pq ----------------
// Wave per row: reduce max/sum, build 256-entry int8 LUT in LDS, rewrite row.
__global__ __launch_bounds__(256)
void softmax_pq(signed char* __restrict__ Sq,
                const float* __restrict__ aattn, const float* __restrict__ aattn2) {
  __shared__ signed char lutS[4 * 256];
  const int lane = threadIdx.x & 63;
  const int wrow = threadIdx.x >> 6;
  const int row = (blockIdx.x << 2) + wrow;
  signed char* p = Sq + ((size_t)row << 11);
  char4 vals[8];
  int vmax = -129;
#pragma unroll
  for (int u = 0; u < 8; ++u) {
    vals[u] = ((const char4*)p)[lane + (u << 6)];
    vmax = max(vmax, (int)vals[u].x);
    vmax = max(vmax, (int)vals[u].y);
    vmax = max(vmax, (int)vals[u].z);
    vmax = max(vmax, (int)vals[u].w);
  }
#pragma unroll
  for (int off = 32; off > 0; off >>= 1)
    vmax = max(vmax, __shfl_xor(vmax, off, 64));
  const float a = aattn[0];
  const float m = a * (float)vmax;
  float l = 0.0f;
#pragma unroll
  for (int u = 0; u < 8; ++u) {
    l += expf(a * (float)vals[u].x - m);
    l += expf(a * (float)vals[u].y - m);
    l += expf(a * (float)vals[u].z - m);
    l += expf(a * (float)vals[u].w - m);
  }
#pragma unroll
  for (int off = 32; off > 0; off >>= 1)
    l += __shfl_xor(l, off, 64);
  // build this row's 256-entry LUT (same fp32 expressions as the verified path)
  const float a2 = aattn2[0];
#pragma unroll
  for (int u = 0; u < 4; ++u) {
    int s = u * 64 + lane - 128;
    float arg;
    {
#pragma clang fp contract(off)
      arg = a * (float)s - m;   // mul-then-sub, matching the softmax path
    }
    float pq = expf(arg) / l / a2;
    lutS[wrow * 256 + u * 64 + lane] = (signed char)(int)rintf(qclip(pq));
  }
  __syncthreads();
  const signed char* lr = lutS + wrow * 256 + 128;
#pragma unroll
  for (int u = 0; u < 8; ++u) {
    char4 o;
    o.x = lr[(int)vals[u].x];
    o.y = lr[(int)vals[u].y];
    o.z = lr[(int)vals[u].z];
    o.w = lr[(int)vals[u].w];
    ((char4*)p)[lane + (u << 6)] = o;
  }
}

// ---------------- PV (i8 MFMA): Pq @ vT^T, 4-way K-split ----------------
// Block = 256 thr = 4 waves over the SAME 16 rows; wave w sums K-quarter
// [w*512,(w+1)*512); exact integer partial sums reduced through LDS.
__global__ __launch_bounds__(256)
void gemm_pv(const signed char* __restrict__ Pq, const signed char* __restrict__ vwsT,
             signed char* __restrict__ ows,
             const float* __restrict__ aattn2, const float* __restrict__ av,
             const float* __restrict__ apa) {
  __shared__ int red[3 * 64 * 17];
  const int t = threadIdx.x;
  const int w = t >> 6, lane = t & 63;
  const int lm = lane & 15, quad = lane >> 4;
  const int i0 = blockIdx.x * 16;
  const int bh = blockIdx.y;
  const int arow = i0 + lm;
  const signed char* Sb = Pq + ((size_t)bh << 22) + ((size_t)arow << 11) + (w << 9) + quad * 16;
  const signed char* Vb = vwsT + ((size_t)bh << 17) + (w << 9);
  i32x4 acc[4] = {};
  for (int j0 = 0; j0 < 512; j0 += 64) {
    i32x4 af = *(const i32x4*)(Sb + j0);
    i32x4 bf[4];
#pragma unroll
    for (int nt = 0; nt < 4; ++nt)
      bf[nt] = *(const i32x4*)(Vb + ((size_t)(nt * 16 + lm) << 11) + j0 + quad * 16);
#pragma unroll
    for (int nt = 0; nt < 4; ++nt)
      acc[nt] = MFMA_I8(af, bf[nt], acc[nt]);
  }
  if (w > 0) {
    int* rw = red + (w - 1) * 1088 + lane * 17;
#pragma unroll
    for (int nt = 0; nt < 4; ++nt)
#pragma unroll
      for (int r = 0; r < 4; ++r)
        rw[nt * 4 + r] = acc[nt][r];
  }
  __syncthreads();
  if (w == 0) {
    const float so = aattn2[0] * av[0];
    const float ipa = apa[0];
    int bb = bh / 6, h = bh % 6;
#pragma unroll
    for (int nt = 0; nt < 4; ++nt) {
      int d = nt * 16 + lm;
#pragma unroll
      for (int r = 0; r < 4; ++r) {
        int s = acc[nt][r] + red[lane * 17 + nt * 4 + r]
              + red[1088 + lane * 17 + nt * 4 + r]
              + red[2176 + lane * 17 + nt * 4 + r];
        int i = i0 + quad * 4 + r;
        ows[(size_t)((bb << 11) + i) * 384 + (h << 6) + d] =
            (signed char)(int)rintf(qclip((float)s * so / ipa));
      }
    }
  }
}

// ---------------- proj (i8 MFMA): [4096,384] @ [384,384]^T * s + bias ----------------
// 64x64 block = 2x2 waves of 32x32.
__global__ __launch_bounds__(256)
void gemm_proj(const signed char* __restrict__ A, const signed char* __restrict__ W,
               const float* __restrict__ bias, float* __restrict__ out,
               const float* __restrict__ apa, const float* __restrict__ apw) {
  const int t = threadIdx.x;
  const int w = t >> 6, lane = t & 63;
  const int lm = lane & 15, quad = lane >> 4;
  const int wm = w >> 1, wn = w & 1;
  const int m0 = blockIdx.x * 64 + wm * 32;
  const int n0 = blockIdx.y * 64 + wn * 32;
  i32x4 acc[2][2] = {};
  for (int k0 = 0; k0 < 384; k0 += 64) {
    i32x4 af[2], bf[2];
#pragma unroll
    for (int mt = 0; mt < 2; ++mt)
      af[mt] = *(const i32x4*)(A + (size_t)(m0 + mt * 16 + lm) * 384 + k0 + quad * 16);
#pragma unroll
    for (int nt = 0; nt < 2; ++nt)
      bf[nt] = *(const i32x4*)(W + (size_t)(n0 + nt * 16 + lm) * 384 + k0 + quad * 16);
#pragma unroll
    for (int mt = 0; mt < 2; ++mt)
#pragma unroll
      for (int nt = 0; nt < 2; ++nt)
        acc[mt][nt] = MFMA_I8(af[mt], bf[nt], acc[mt][nt]);
  }
  const float sAB = apa[0] * apw[0];
#pragma unroll
  for (int mt = 0; mt < 2; ++mt) {
#pragma unroll
    for (int nt = 0; nt < 2; ++nt) {
      int cg = n0 + nt * 16 + lm;
#pragma unroll
      for (int r = 0; r < 4; ++r) {
        int m = m0 + mt * 16 + quad * 4 + r;
        out[(size_t)m * 384 + cg] = (float)acc[mt][nt][r] * sAB + bias[cg];
      }
    }
  }
}

extern "C" void kernel_launch(void* const* d_in, const int* in_sizes, int n_in,
                              void* d_out, int out_size, void* d_ws, size_t ws_size,
                              hipStream_t stream) {
  const float* x        = (const float*)d_in[0];
  const float* w_qkv    = (const float*)d_in[1];
  const float* w_proj   = (const float*)d_in[2];
  const float* b_proj   = (const float*)d_in[3];
  const float* a_qkv_w  = (const float*)d_in[4];
  const float* a_qkv_a  = (const float*)d_in[5];
  const float* a_proj_w = (const float*)d_in[6];
  const float* a_proj_a = (const float*)d_in[7];
  const float* a_q      = (const float*)d_in[8];
  const float* a_k      = (const float*)d_in[9];
  const float* a_v      = (const float*)d_in[10];
  const float* a_attn   = (const float*)d_in[11];
  const float* a_attn2  = (const float*)d_in[12];

  char* wsb = (char*)d_ws;
  signed char* xq   = (signed char*)(wsb + 0);        // 4096*384      = 1,572,864 B
  signed char* wqq  = (signed char*)(wsb + 1572864);  // 1152*384      =   442,368 B
  signed char* wpq  = (signed char*)(wsb + 2015232);  //  384*384      =   147,456 B
  signed char* qws  = (signed char*)(wsb + 2162688);  // 12*2048*64    = 1,572,864 B
  signed char* kws  = (signed char*)(wsb + 3735552);  // same
  signed char* vwsT = (signed char*)(wsb + 5308416);  // same, [bh,d,n]
  signed char* ows  = (signed char*)(wsb + 6881280);  // 4096*384      = 1,572,864 B
  signed char* Sq   = (signed char*)(wsb + 8454144);  // 12*2048*2048  = 50,331,648 B (Sq -> Pq in place)
  // total ws usage: 58,785,792 bytes

  quant16<<<384, 256, 0, stream>>>(x, xq, a_qkv_a, 98304);
  quant16<<<108, 256, 0, stream>>>(w_qkv, wqq, a_qkv_w, 27648);
  quant16<<<36, 256, 0, stream>>>(w_proj, wpq, a_proj_w, 9216);
  gemm_qkv<<<dim3(32, 9), 256, 0, stream>>>(xq, wqq, qws, kws, vwsT,
                                            a_qkv_a, a_qkv_w, a_q, a_k, a_v);
  gemm_scores<<<dim3(16, 16, 12), 256, 0, stream>>>(qws, kws, Sq, a_q, a_k, a_attn);
  softmax_pq<<<6144, 256, 0, stream>>>(Sq, a_attn, a_attn2);
  gemm_pv<<<dim3(128, 12), 256, 0, stream>>>(Sq, vwsT, ows, a_attn2, a_v, a_proj_a);
  gemm_proj<<<dim3(64, 6), 256, 0, stream>>>(ows, wpq, b_proj, (float*)d_out,
                                             a_proj_a, a_proj_w);
}

// Round 5
// 200.171 us; speedup vs baseline: 2.3376x; 1.0548x over previous
//
#include <hip/hip_runtime.h>
#include <math.h>

// B=2, N=2048, C=384, H=6, D=64.  All quantized tensors hold INTEGER values
// (round(clip(x/a))) stored as int8; alpha scales are factored into epilogues
// with expressions identical to the verified baseline (absmax 0.0).
// All GEMMs use v_mfma_i32_16x16x64_i8: i32 accumulation is exact, and every
// final sum is < 2^24, so the (float) conversion in the epilogue reproduces
// the f32-accumulated value bit-exactly.
//
// Round 5: softmax fused into PV.  softmax_pv stages a 16-row Sq tile in LDS,
// computes row stats + int8 LUT with the SAME lane order / reduce order /
// fp expressions as the verified standalone softmax (bit-identical l,m),
// builds A-fragments through the LUT directly into registers, then runs the
// unchanged 4-way K-split i8 GEMM.  Pq is never written to HBM (-100 MB).

typedef int i32x4 __attribute__((ext_vector_type(4)));

#define MFMA_I8(a, b, c) __builtin_amdgcn_mfma_i32_16x16x64_i8(a, b, c, 0, 0, 0)

__device__ __forceinline__ float qclip(float s) {
  return fminf(fmaxf(s, -128.0f), 127.0f);
}

// ---------------- elementwise quantize -> int8 (16 elems/thread) ----------------
__global__ __launch_bounds__(256)
void quant16(const float* __restrict__ in, signed char* __restrict__ out,
             const float* __restrict__ alpha, int n16) {
  int i = blockIdx.x * 256 + threadIdx.x;
  if (i >= n16) return;
  float a = alpha[0];
  const float4* p = (const float4*)in + 4 * (size_t)i;
  union { uint4 u; signed char c[16]; } o;
#pragma unroll
  for (int u = 0; u < 4; ++u) {
    float4 v = p[u];
    o.c[4 * u + 0] = (signed char)(int)rintf(qclip(v.x / a));
    o.c[4 * u + 1] = (signed char)(int)rintf(qclip(v.y / a));
    o.c[4 * u + 2] = (signed char)(int)rintf(qclip(v.z / a));
    o.c[4 * u + 3] = (signed char)(int)rintf(qclip(v.w / a));
  }
  *(uint4*)(out + 16 * (size_t)i) = o.u;
}

// ---------------- QKV GEMM (i8 MFMA): [4096,384] @ [1152,384]^T ----------------
__global__ __launch_bounds__(256)
void gemm_qkv(const signed char* __restrict__ A, const signed char* __restrict__ W,
              signed char* __restrict__ qws, signed char* __restrict__ kws,
              signed char* __restrict__ vwsT,
              const float* __restrict__ aa, const float* __restrict__ aw,
              const float* __restrict__ aq, const float* __restrict__ ak,
              const float* __restrict__ av) {
  const int t = threadIdx.x;
  const int w = t >> 6, lane = t & 63;
  const int lm = lane & 15, quad = lane >> 4;
  const int wm = w >> 1, wn = w & 1;
  const int m0 = blockIdx.x * 128 + wm * 64;
  const int n0 = blockIdx.y * 128 + wn * 64;
  i32x4 acc[4][4] = {};
  for (int k0 = 0; k0 < 384; k0 += 64) {
    i32x4 af[4], bf[4];
#pragma unroll
    for (int mt = 0; mt < 4; ++mt)
      af[mt] = *(const i32x4*)(A + (size_t)(m0 + mt * 16 + lm) * 384 + k0 + quad * 16);
#pragma unroll
    for (int nt = 0; nt < 4; ++nt)
      bf[nt] = *(const i32x4*)(W + (size_t)(n0 + nt * 16 + lm) * 384 + k0 + quad * 16);
#pragma unroll
    for (int mt = 0; mt < 4; ++mt)
#pragma unroll
      for (int nt = 0; nt < 4; ++nt)
        acc[mt][nt] = MFMA_I8(af[mt], bf[nt], acc[mt][nt]);
  }
  const float sAB = aa[0] * aw[0];
  const float vaq = aq[0], vak = ak[0], vav = av[0];
#pragma unroll
  for (int mt = 0; mt < 4; ++mt) {
#pragma unroll
    for (int nt = 0; nt < 4; ++nt) {
      int cg = n0 + nt * 16 + lm;
      int t3 = cg / 384;
      int rem = cg - t3 * 384;
      int h = rem >> 6, d = rem & 63;
#pragma unroll
      for (int r = 0; r < 4; ++r) {
        int m = m0 + mt * 16 + quad * 4 + r;
        int bb = m >> 11, nn = m & 2047;
        int bh = bb * 6 + h;
        float val = (float)acc[mt][nt][r] * sAB;
        if (t3 == 0) {
          qws[((size_t)(bh * 2048 + nn) << 6) + d] = (signed char)(int)rintf(qclip(val / vaq));
        } else if (t3 == 1) {
          kws[((size_t)(bh * 2048 + nn) << 6) + d] = (signed char)(int)rintf(qclip(val / vak));
        } else {
          vwsT[((size_t)((bh << 6) + d) << 11) + nn] = (signed char)(int)rintf(qclip(val / vav));
        }
      }
    }
  }
}

// ---------------- scores (i8 MFMA): S = q @ k^T, requant -> int8 ----------------
__global__ __launch_bounds__(256)
void gemm_scores(const signed char* __restrict__ qws, const signed char* __restrict__ kws,
                 signed char* __restrict__ Sq,
                 const float* __restrict__ aq, const float* __restrict__ ak,
                 const float* __restrict__ aattn) {
  const int t = threadIdx.x;
  const int w = t >> 6, lane = t & 63;
  const int lm = lane & 15, quad = lane >> 4;
  const int wm = w >> 1, wn = w & 1;
  const int m0 = blockIdx.x * 128 + wm * 64;
  const int n0 = blockIdx.y * 128 + wn * 64;
  const int bh = blockIdx.z;
  const signed char* Aq = qws + ((size_t)bh << 17);
  const signed char* Bk = kws + ((size_t)bh << 17);
  i32x4 acc[4][4] = {};
  i32x4 af[4], bf[4];
#pragma unroll
  for (int mt = 0; mt < 4; ++mt)
    af[mt] = *(const i32x4*)(Aq + ((size_t)(m0 + mt * 16 + lm) << 6) + quad * 16);
#pragma unroll
  for (int nt = 0; nt < 4; ++nt)
    bf[nt] = *(const i32x4*)(Bk + ((size_t)(n0 + nt * 16 + lm) << 6) + quad * 16);
#pragma unroll
  for (int mt = 0; mt < 4; ++mt)
#pragma unroll
    for (int nt = 0; nt < 4; ++nt)
      acc[mt][nt] = MFMA_I8(af[mt], bf[nt], acc[mt][nt]);
  const float sc = aq[0] * ak[0] * 0.125f;
  const float ia = aattn[0];
  signed char* Sb = Sq + ((size_t)bh << 22);
#pragma unroll
  for (int mt = 0; mt < 4; ++mt) {
#pragma unroll
    for (int nt = 0; nt < 4; ++nt) {
      int col = n0 + nt * 16 + lm;
#pragma unroll
      for (int r = 0; r < 4; ++r) {
        int row = m0 + mt * 16 + quad * 4 + r;
        float sv = (float)acc[mt][nt][r] * sc;
        Sb[((size_t)row << 11) + col] = (signed char)(int)rintf(qclip(sv / ia));
      }
    }
  }
}

// ---------------- fused softmax + PV (i8 MFMA) ----------------
// Block = 256 thr = 4 waves, 16 Q-rows, full K=2048.
// Phase 1: contiguous 32KB Sq tile -> LDS (rows padded to 2064 B).
// Phase 2: per-row stats + int8 LUT, bit-identical order to the verified
//          standalone softmax (wave-per-row, char4 lane+u*64, xor butterfly).
// Phase 3: each lane LUT-gathers exactly its own 128 A-bytes into registers.
// Phase 4: 4-way K-split i8 GEMM (wave w owns K quarter), V from global.
// Phase 5: exact integer LDS reduce (aliases tile) + requant epilogue.
#define TROW 2064
__global__ __launch_bounds__(256)
void softmax_pv(const signed char* __restrict__ Sq, const signed char* __restrict__ vwsT,
                signed char* __restrict__ ows,
                const float* __restrict__ aattn, const float* __restrict__ aattn2,
                const float* __restrict__ av, const float* __restrict__ apa) {
  __shared__ signed char tileS[16 * TROW];   // 33,024 B (reduce buffer aliases)
  __shared__ signed char lutS[16 * 256];     //  4,096 B
  const int t = threadIdx.x;
  const int w = t >> 6, lane = t & 63;
  const int lm = lane & 15, quad = lane >> 4;
  const int i0 = blockIdx.x * 16;
  const int bh = blockIdx.y;

  // ---- phase 1: load 16 contiguous rows (32 KB) into padded LDS tile
  {
    const uint4* src = (const uint4*)(Sq + ((size_t)bh << 22) + ((size_t)i0 << 11));
#pragma unroll
    for (int u = 0; u < 8; ++u) {
      int chunk = t + u * 256;           // 16-byte chunk index, 0..2047
      int row = chunk >> 7, col = chunk & 127;
      *(uint4*)(tileS + row * TROW + col * 16) = src[chunk];
    }
  }
  __syncthreads();

  // ---- phase 2: stats + LUT, wave w handles rows 4w..4w+3 (order as verified)
  const float a = aattn[0];
  const float a2 = aattn2[0];
#pragma unroll
  for (int rr = 0; rr < 4; ++rr) {
    const int row = w * 4 + rr;
    const char4* prow = (const char4*)(tileS + row * TROW);
    char4 vals[8];
    int vmax = -129;
#pragma unroll
    for (int u = 0; u < 8; ++u) {
      vals[u] = prow[lane + (u << 6)];
      vmax = max(vmax, (int)vals[u].x);
      vmax = max(vmax, (int)vals[u].y);
      vmax = max(vmax, (int)vals[u].z);
      vmax = max(vmax, (int)vals[u].w);
    }
#pragma unroll
    for (int off = 32; off > 0; off >>= 1)
      vmax = max(vmax, __shfl_xor(vmax, off, 64));
    const float m = a * (float)vmax;
    float l = 0.0f;
#pragma unroll
    for (int u = 0; u < 8; ++u) {
      l += expf(a * (float)vals[u].x - m);
      l += expf(a * (float)vals[u].y - m);
      l += expf(a * (float)vals[u].z - m);
      l += expf(a * (float)vals[u].w - m);
    }
#pragma unroll
    for (int off = 32; off > 0; off >>= 1)
      l += __shfl_xor(l, off, 64);
#pragma unroll
    for (int u = 0; u < 4; ++u) {
      int s = u * 64 + lane - 128;
      float arg;
      {
#pragma clang fp contract(off)
        arg = a * (float)s - m;   // mul-then-sub, matching the softmax path
      }
      float pq = expf(arg) / l / a2;
      lutS[row * 256 + u * 64 + lane] = (signed char)(int)rintf(qclip(pq));
    }
  }
  __syncthreads();

  // ---- phase 3: build this lane's A-fragments through the LUT
  i32x4 areg[8];
  {
    const signed char* lr = lutS + lm * 256 + 128;
    const signed char* srow = tileS + lm * TROW + (w << 9) + quad * 16;
#pragma unroll
    for (int js = 0; js < 8; ++js) {
      union { uint4 u; signed char c[16]; } sv;
      sv.u = *(const uint4*)(srow + js * 64);
      union { i32x4 v; signed char c[16]; } dv;
#pragma unroll
      for (int b = 0; b < 16; ++b) dv.c[b] = lr[(int)sv.c[b]];
      areg[js] = dv.v;
    }
  }

  // ---- phase 4: K-split GEMM, wave w sums K quarter [w*512,(w+1)*512)
  const signed char* Vb = vwsT + ((size_t)bh << 17) + (w << 9);
  i32x4 acc[4] = {};
#pragma unroll
  for (int js = 0; js < 8; ++js) {
    int j0 = js * 64;
    i32x4 bf[4];
#pragma unroll
    for (int nt = 0; nt < 4; ++nt)
      bf[nt] = *(const i32x4*)(Vb + ((size_t)(nt * 16 + lm) << 11) + j0 + quad * 16);
#pragma unroll
    for (int nt = 0; nt < 4; ++nt)
      acc[nt] = MFMA_I8(areg[js], bf[nt], acc[nt]);
  }

  // ---- phase 5: exact integer reduce (reduce buffer aliases the tile)
  int* red = (int*)tileS;
  __syncthreads();
  if (w > 0) {
    int* rw = red + (w - 1) * 1088 + lane * 17;
#pragma unroll
    for (int nt = 0; nt < 4; ++nt)
#pragma unroll
      for (int r = 0; r < 4; ++r)
        rw[nt * 4 + r] = acc[nt][r];
  }
  __syncthreads();
  if (w == 0) {
    const float so = a2 * av[0];
    const float ipa = apa[0];
    int bb = bh / 6, h = bh % 6;
#pragma unroll
    for (int nt = 0; nt < 4; ++nt) {
      int d = nt * 16 + lm;
#pragma unroll
      for (int r = 0; r < 4; ++r) {
        int s = acc[nt][r] + red[lane * 17 + nt * 4 + r]
              + red[1088 + lane * 17 + nt * 4 + r]
              + red[2176 + lane * 17 + nt * 4 + r];
        int i = i0 + quad * 4 + r;
        ows[(size_t)((bb << 11) + i) * 384 + (h << 6) + d] =
            (signed char)(int)rintf(qclip((float)s * so / ipa));
      }
    }
  }
}

// ---------------- proj (i8 MFMA): [4096,384] @ [384,384]^T * s + bias ----------------
__global__ __launch_bounds__(256)
void gemm_proj(const signed char* __restrict__ A, const signed char* __restrict__ W,
               const float* __restrict__ bias, float* __restrict__ out,
               const float* __restrict__ apa, const float* __restrict__ apw) {
  const int t = threadIdx.x;
  const int w = t >> 6, lane = t & 63;
  const int lm = lane & 15, quad = lane >> 4;
  const int wm = w >> 1, wn = w & 1;
  const int m0 = blockIdx.x * 64 + wm * 32;
  const int n0 = blockIdx.y * 64 + wn * 32;
  i32x4 acc[2][2] = {};
  for (int k0 = 0; k0 < 384; k0 += 64) {
    i32x4 af[2], bf[2];
#pragma unroll
    for (int mt = 0; mt < 2; ++mt)
      af[mt] = *(const i32x4*)(A + (size_t)(m0 + mt * 16 + lm) * 384 + k0 + quad * 16);
#pragma unroll
    for (int nt = 0; nt < 2; ++nt)
      bf[nt] = *(const i32x4*)(W + (size_t)(n0 + nt * 16 + lm) * 384 + k0 + quad * 16);
#pragma unroll
    for (int mt = 0; mt < 2; ++mt)
#pragma unroll
      for (int nt = 0; nt < 2; ++nt)
        acc[mt][nt] = MFMA_I8(af[mt], bf[nt], acc[mt][nt]);
  }
  const float sAB = apa[0] * apw[0];
#pragma unroll
  for (int mt = 0; mt < 2; ++mt) {
#pragma unroll
    for (int nt = 0; nt < 2; ++nt) {
      int cg = n0 + nt * 16 + lm;
#pragma unroll
      for (int r = 0; r < 4; ++r) {
        int m = m0 + mt * 16 + quad * 4 + r;
        out[(size_t)m * 384 + cg] = (float)acc[mt][nt][r] * sAB + bias[cg];
      }
    }
  }
}

extern "C" void kernel_launch(void* const* d_in, const int* in_sizes, int n_in,
                              void* d_out, int out_size, void* d_ws, size_t ws_size,
                              hipStream_t stream) {
  const float* x        = (const float*)d_in[0];
  const float* w_qkv    = (const float*)d_in[1];
  const float* w_proj   = (const float*)d_in[2];
  const float* b_proj   = (const float*)d_in[3];
  const float* a_qkv_w  = (const float*)d_in[4];
  const float* a_qkv_a  = (const float*)d_in[5];
  const float* a_proj_w = (const float*)d_in[6];
  const float* a_proj_a = (const float*)d_in[7];
  const float* a_q      = (const float*)d_in[8];
  const float* a_k      = (const float*)d_in[9];
  const float* a_v      = (const float*)d_in[10];
  const float* a_attn   = (const float*)d_in[11];
  const float* a_attn2  = (const float*)d_in[12];

  char* wsb = (char*)d_ws;
  signed char* xq   = (signed char*)(wsb + 0);        // 4096*384      = 1,572,864 B
  signed char* wqq  = (signed char*)(wsb + 1572864);  // 1152*384      =   442,368 B
  signed char* wpq  = (signed char*)(wsb + 2015232);  //  384*384      =   147,456 B
  signed char* qws  = (signed char*)(wsb + 2162688);  // 12*2048*64    = 1,572,864 B
  signed char* kws  = (signed char*)(wsb + 3735552);  // same
  signed char* vwsT = (signed char*)(wsb + 5308416);  // same, [bh,d,n]
  signed char* ows  = (signed char*)(wsb + 6881280);  // 4096*384      = 1,572,864 B
  signed char* Sq   = (signed char*)(wsb + 8454144);  // 12*2048*2048  = 50,331,648 B
  // total ws usage: 58,785,792 bytes

  quant16<<<384, 256, 0, stream>>>(x, xq, a_qkv_a, 98304);
  quant16<<<108, 256, 0, stream>>>(w_qkv, wqq, a_qkv_w, 27648);
  quant16<<<36, 256, 0, stream>>>(w_proj, wpq, a_proj_w, 9216);
  gemm_qkv<<<dim3(32, 9), 256, 0, stream>>>(xq, wqq, qws, kws, vwsT,
                                            a_qkv_a, a_qkv_w, a_q, a_k, a_v);
  gemm_scores<<<dim3(16, 16, 12), 256, 0, stream>>>(qws, kws, Sq, a_q, a_k, a_attn);
  softmax_pv<<<dim3(128, 12), 256, 0, stream>>>(Sq, vwsT, ows,
                                                a_attn, a_attn2, a_v, a_proj_a);
  gemm_proj<<<dim3(64, 6), 256, 0, stream>>>(ows, wpq, b_proj, (float*)d_out,
                                             a_proj_a, a_proj_w);
}

// Round 6
// 184.875 us; speedup vs baseline: 2.5310x; 1.0827x over previous
//
#include <hip/hip_runtime.h>
#include <math.h>

// B=2, N=2048, C=384, H=6, D=64.  All quantized tensors hold INTEGER values
// (round(clip(x/a))) stored as int8; alpha scales are factored into epilogues
// with expressions identical to the verified baseline (absmax 0.0).
// All GEMMs use v_mfma_i32_16x16x64_i8 (i32 accumulation exact; all sums
// < 2^24 so the (float) conversion is bit-exact).
//
// Round 6: scores fused into the softmax+PV kernel (S never touches HBM).
// The block computes its own 16x2048 S-tile with operand-swapped MFMA so each
// lane packs 4 consecutive k-cols of one q-row -> conflict-free ds_write_b32.
// The 50M per-element expf's are replaced by a precomputed global table
// E2[vmax][s] = expf(a*s - a*vmax) (65536 entries, same source expression as
// the verified per-element path); row sums gather E2 slices from LDS in the
// identical summation order, so l is reproduced to the ulp.

typedef int i32x4 __attribute__((ext_vector_type(4)));

#define MFMA_I8(a, b, c) __builtin_amdgcn_mfma_i32_16x16x64_i8(a, b, c, 0, 0, 0)

__device__ __forceinline__ float qclip(float s) {
  return fminf(fmaxf(s, -128.0f), 127.0f);
}

// ---------------- elementwise quantize -> int8 (16 elems/thread) ----------------
__global__ __launch_bounds__(256)
void quant16(const float* __restrict__ in, signed char* __restrict__ out,
             const float* __restrict__ alpha, int n16) {
  int i = blockIdx.x * 256 + threadIdx.x;
  if (i >= n16) return;
  float a = alpha[0];
  const float4* p = (const float4*)in + 4 * (size_t)i;
  union { uint4 u; signed char c[16]; } o;
#pragma unroll
  for (int u = 0; u < 4; ++u) {
    float4 v = p[u];
    o.c[4 * u + 0] = (signed char)(int)rintf(qclip(v.x / a));
    o.c[4 * u + 1] = (signed char)(int)rintf(qclip(v.y / a));
    o.c[4 * u + 2] = (signed char)(int)rintf(qclip(v.z / a));
    o.c[4 * u + 3] = (signed char)(int)rintf(qclip(v.w / a));
  }
  *(uint4*)(out + 16 * (size_t)i) = o.u;
}

// ---------------- exp table: E2[(vmax+128)*256 + (s+128)] = expf(a*s - a*vmax) ----------------
// Same source expression as the verified per-element softmax sum path.
__global__ __launch_bounds__(256)
void exp_table(float* __restrict__ E2, const float* __restrict__ aattn) {
  int i = blockIdx.x * 256 + threadIdx.x;   // 0..65535
  float a = aattn[0];
  int vm = (i >> 8) - 128;
  int s = (i & 255) - 128;
  float m = a * (float)vm;
  E2[i] = expf(a * (float)s - m);
}

// ---------------- QKV GEMM (i8 MFMA): [4096,384] @ [1152,384]^T ----------------
__global__ __launch_bounds__(256)
void gemm_qkv(const signed char* __restrict__ A, const signed char* __restrict__ W,
              signed char* __restrict__ qws, signed char* __restrict__ kws,
              signed char* __restrict__ vwsT,
              const float* __restrict__ aa, const float* __restrict__ aw,
              const float* __restrict__ aq, const float* __restrict__ ak,
              const float* __restrict__ av) {
  const int t = threadIdx.x;
  const int w = t >> 6, lane = t & 63;
  const int lm = lane & 15, quad = lane >> 4;
  const int wm = w >> 1, wn = w & 1;
  const int m0 = blockIdx.x * 128 + wm * 64;
  const int n0 = blockIdx.y * 128 + wn * 64;
  i32x4 acc[4][4] = {};
  for (int k0 = 0; k0 < 384; k0 += 64) {
    i32x4 af[4], bf[4];
#pragma unroll
    for (int mt = 0; mt < 4; ++mt)
      af[mt] = *(const i32x4*)(A + (size_t)(m0 + mt * 16 + lm) * 384 + k0 + quad * 16);
#pragma unroll
    for (int nt = 0; nt < 4; ++nt)
      bf[nt] = *(const i32x4*)(W + (size_t)(n0 + nt * 16 + lm) * 384 + k0 + quad * 16);
#pragma unroll
    for (int mt = 0; mt < 4; ++mt)
#pragma unroll
      for (int nt = 0; nt < 4; ++nt)
        acc[mt][nt] = MFMA_I8(af[mt], bf[nt], acc[mt][nt]);
  }
  const float sAB = aa[0] * aw[0];
  const float vaq = aq[0], vak = ak[0], vav = av[0];
#pragma unroll
  for (int mt = 0; mt < 4; ++mt) {
#pragma unroll
    for (int nt = 0; nt < 4; ++nt) {
      int cg = n0 + nt * 16 + lm;
      int t3 = cg / 384;
      int rem = cg - t3 * 384;
      int h = rem >> 6, d = rem & 63;
#pragma unroll
      for (int r = 0; r < 4; ++r) {
        int m = m0 + mt * 16 + quad * 4 + r;
        int bb = m >> 11, nn = m & 2047;
        int bh = bb * 6 + h;
        float val = (float)acc[mt][nt][r] * sAB;
        if (t3 == 0) {
          qws[((size_t)(bh * 2048 + nn) << 6) + d] = (signed char)(int)rintf(qclip(val / vaq));
        } else if (t3 == 1) {
          kws[((size_t)(bh * 2048 + nn) << 6) + d] = (signed char)(int)rintf(qclip(val / vak));
        } else {
          vwsT[((size_t)((bh << 6) + d) << 11) + nn] = (signed char)(int)rintf(qclip(val / vav));
        }
      }
    }
  }
}

// ---------------- fully fused attention: S = qK^T -> softmax -> PV ----------------
// Block = 256 thr = 4 waves, 16 q-rows, one bh.
// B: S^T-MFMA per 16-col chunk; lane packs 4 consecutive k-cols of q-row lm
//    into a dword -> conflict-free ds_write_b32 into padded tile.
// C: per-row stats (verified lane order), stage E2[vmax] slice -> LDS,
//    sum via ordered gathers (summands bit-identical to expf path),
//    P-LUT entries computed from the staged slice already in registers.
// D: LUT int8 rows overlay the Ef region (after barrier).
// E: lane LUT-gathers its own 128 A-bytes; 4-way K-split i8 GEMM.
// F: exact integer LDS reduce (aliases tile) + requant epilogue.
#define TROW 2064
__global__ __launch_bounds__(256)
void attn_fused(const signed char* __restrict__ qws, const signed char* __restrict__ kws,
                const signed char* __restrict__ vwsT, const float* __restrict__ E2,
                signed char* __restrict__ ows,
                const float* __restrict__ aq, const float* __restrict__ ak,
                const float* __restrict__ aattn, const float* __restrict__ aattn2,
                const float* __restrict__ av, const float* __restrict__ apa) {
  __shared__ signed char tileS[16 * TROW];   // 33,024 B (int reduce aliases)
  __shared__ float EfS[16 * 256];            // 16,384 B (int8 LUT overlays)
  const int t = threadIdx.x;
  const int w = t >> 6, lane = t & 63;
  const int lm = lane & 15, quad = lane >> 4;
  const int i0 = blockIdx.x * 16;
  const int bh = blockIdx.y;

  const signed char* Qb = qws + ((size_t)bh << 17);
  const signed char* Kb = kws + ((size_t)bh << 17);

  // ---- phase B: scores tile.  bq = this block's 16 q-rows (B operand).
  i32x4 bq = *(const i32x4*)(Qb + ((size_t)(i0 + lm) << 6) + quad * 16);
  const float sc = aq[0] * ak[0] * 0.125f;
  const float ia = aattn[0];
#pragma unroll 4
  for (int ct = 0; ct < 32; ++ct) {
    int col0 = (w << 9) + ct * 16;
    i32x4 akf = *(const i32x4*)(Kb + ((size_t)(col0 + lm) << 6) + quad * 16);
    i32x4 z = {};
    i32x4 acc = MFMA_I8(akf, bq, z);
    // acc[r] = S[q-row i0+lm][k-col col0 + quad*4 + r]
    union { unsigned int u; signed char c[4]; } pk;
#pragma unroll
    for (int r = 0; r < 4; ++r) {
      float sv = (float)acc[r] * sc;
      pk.c[r] = (signed char)(int)rintf(qclip(sv / ia));
    }
    *(unsigned int*)(tileS + lm * TROW + col0 + quad * 4) = pk.u;
  }
  __syncthreads();

  // ---- phase C: per-row stats + LUT values (wave w owns rows 4w..4w+3)
  const float a2 = aattn2[0];
  unsigned int pqpack[4];
  signed char* lut8 = (signed char*)EfS;
#pragma unroll
  for (int rr = 0; rr < 4; ++rr) {
    const int row = w * 4 + rr;
    const char4* prow = (const char4*)(tileS + row * TROW);
    char4 vals[8];
    int vmax = -129;
#pragma unroll
    for (int u = 0; u < 8; ++u) {
      vals[u] = prow[lane + (u << 6)];
      vmax = max(vmax, (int)vals[u].x);
      vmax = max(vmax, (int)vals[u].y);
      vmax = max(vmax, (int)vals[u].z);
      vmax = max(vmax, (int)vals[u].w);
    }
#pragma unroll
    for (int off = 32; off > 0; off >>= 1)
      vmax = max(vmax, __shfl_xor(vmax, off, 64));
    // stage this row's exp slice: lane holds entries lane*4..lane*4+3
    float4 ef = *(const float4*)(E2 + (((vmax + 128) << 8) + (lane << 2)));
    *(float4*)(EfS + (row << 8) + (lane << 2)) = ef;
    const float* Er = EfS + (row << 8) + 128;
    float l = 0.0f;
#pragma unroll
    for (int u = 0; u < 8; ++u) {
      l += Er[(int)vals[u].x];
      l += Er[(int)vals[u].y];
      l += Er[(int)vals[u].z];
      l += Er[(int)vals[u].w];
    }
#pragma unroll
    for (int off = 32; off > 0; off >>= 1)
      l += __shfl_xor(l, off, 64);
    // LUT entries for s = lane*4+j-128 from the staged slice (in regs)
    union { unsigned int u; signed char c[4]; } pk;
    pk.c[0] = (signed char)(int)rintf(qclip(ef.x / l / a2));
    pk.c[1] = (signed char)(int)rintf(qclip(ef.y / l / a2));
    pk.c[2] = (signed char)(int)rintf(qclip(ef.z / l / a2));
    pk.c[3] = (signed char)(int)rintf(qclip(ef.w / l / a2));
    pqpack[rr] = pk.u;
  }
  __syncthreads();

  // ---- phase D: write int8 LUT rows (overlay Ef region)
#pragma unroll
  for (int rr = 0; rr < 4; ++rr)
    *(unsigned int*)(lut8 + (((w * 4 + rr) << 8) + (lane << 2))) = pqpack[rr];
  __syncthreads();

  // ---- phase E1: build this lane's A-fragments through the LUT
  i32x4 areg[8];
  {
    const signed char* lr = lut8 + lm * 256 + 128;
    const signed char* srow = tileS + lm * TROW + (w << 9) + quad * 16;
#pragma unroll
    for (int js = 0; js < 8; ++js) {
      union { uint4 u; signed char c[16]; } sv;
      sv.u = *(const uint4*)(srow + js * 64);
      union { i32x4 v; signed char c[16]; } dv;
#pragma unroll
      for (int b = 0; b < 16; ++b) dv.c[b] = lr[(int)sv.c[b]];
      areg[js] = dv.v;
    }
  }

  // ---- phase E2: K-split GEMM, wave w sums K quarter [w*512,(w+1)*512)
  const signed char* Vb = vwsT + ((size_t)bh << 17) + (w << 9);
  i32x4 acc[4] = {};
#pragma unroll
  for (int js = 0; js < 8; ++js) {
    int j0 = js * 64;
    i32x4 bf[4];
#pragma unroll
    for (int nt = 0; nt < 4; ++nt)
      bf[nt] = *(const i32x4*)(Vb + ((size_t)(nt * 16 + lm) << 11) + j0 + quad * 16);
#pragma unroll
    for (int nt = 0; nt < 4; ++nt)
      acc[nt] = MFMA_I8(areg[js], bf[nt], acc[nt]);
  }

  // ---- phase F: exact integer reduce (aliases tile) + epilogue
  int* red = (int*)tileS;
  __syncthreads();
  if (w > 0) {
    int* rw = red + (w - 1) * 1088 + lane * 17;
#pragma unroll
    for (int nt = 0; nt < 4; ++nt)
#pragma unroll
      for (int r = 0; r < 4; ++r)
        rw[nt * 4 + r] = acc[nt][r];
  }
  __syncthreads();
  if (w == 0) {
    const float so = a2 * av[0];
    const float ipa = apa[0];
    int bb = bh / 6, h = bh % 6;
#pragma unroll
    for (int nt = 0; nt < 4; ++nt) {
      int d = nt * 16 + lm;
#pragma unroll
      for (int r = 0; r < 4; ++r) {
        int s = acc[nt][r] + red[lane * 17 + nt * 4 + r]
              + red[1088 + lane * 17 + nt * 4 + r]
              + red[2176 + lane * 17 + nt * 4 + r];
        int i = i0 + quad * 4 + r;
        ows[(size_t)((bb << 11) + i) * 384 + (h << 6) + d] =
            (signed char)(int)rintf(qclip((float)s * so / ipa));
      }
    }
  }
}

// ---------------- proj (i8 MFMA): [4096,384] @ [384,384]^T * s + bias ----------------
__global__ __launch_bounds__(256)
void gemm_proj(const signed char* __restrict__ A, const signed char* __restrict__ W,
               const float* __restrict__ bias, float* __restrict__ out,
               const float* __restrict__ apa, const float* __restrict__ apw) {
  const int t = threadIdx.x;
  const int w = t >> 6, lane = t & 63;
  const int lm = lane & 15, quad = lane >> 4;
  const int wm = w >> 1, wn = w & 1;
  const int m0 = blockIdx.x * 64 + wm * 32;
  const int n0 = blockIdx.y * 64 + wn * 32;
  i32x4 acc[2][2] = {};
  for (int k0 = 0; k0 < 384; k0 += 64) {
    i32x4 af[2], bf[2];
#pragma unroll
    for (int mt = 0; mt < 2; ++mt)
      af[mt] = *(const i32x4*)(A + (size_t)(m0 + mt * 16 + lm) * 384 + k0 + quad * 16);
#pragma unroll
    for (int nt = 0; nt < 2; ++nt)
      bf[nt] = *(const i32x4*)(W + (size_t)(n0 + nt * 16 + lm) * 384 + k0 + quad * 16);
#pragma unroll
    for (int mt = 0; mt < 2; ++mt)
#pragma unroll
      for (int nt = 0; nt < 2; ++nt)
        acc[mt][nt] = MFMA_I8(af[mt], bf[nt], acc[mt][nt]);
  }
  const float sAB = apa[0] * apw[0];
#pragma unroll
  for (int mt = 0; mt < 2; ++mt) {
#pragma unroll
    for (int nt = 0; nt < 2; ++nt) {
      int cg = n0 + nt * 16 + lm;
#pragma unroll
      for (int r = 0; r < 4; ++r) {
        int m = m0 + mt * 16 + quad * 4 + r;
        out[(size_t)m * 384 + cg] = (float)acc[mt][nt][r] * sAB + bias[cg];
      }
    }
  }
}

extern "C" void kernel_launch(void* const* d_in, const int* in_sizes, int n_in,
                              void* d_out, int out_size, void* d_ws, size_t ws_size,
                              hipStream_t stream) {
  const float* x        = (const float*)d_in[0];
  const float* w_qkv    = (const float*)d_in[1];
  const float* w_proj   = (const float*)d_in[2];
  const float* b_proj   = (const float*)d_in[3];
  const float* a_qkv_w  = (const float*)d_in[4];
  const float* a_qkv_a  = (const float*)d_in[5];
  const float* a_proj_w = (const float*)d_in[6];
  const float* a_proj_a = (const float*)d_in[7];
  const float* a_q      = (const float*)d_in[8];
  const float* a_k      = (const float*)d_in[9];
  const float* a_v      = (const float*)d_in[10];
  const float* a_attn   = (const float*)d_in[11];
  const float* a_attn2  = (const float*)d_in[12];

  char* wsb = (char*)d_ws;
  signed char* xq   = (signed char*)(wsb + 0);        // 4096*384      = 1,572,864 B
  signed char* wqq  = (signed char*)(wsb + 1572864);  // 1152*384      =   442,368 B
  signed char* wpq  = (signed char*)(wsb + 2015232);  //  384*384      =   147,456 B
  signed char* qws  = (signed char*)(wsb + 2162688);  // 12*2048*64    = 1,572,864 B
  signed char* kws  = (signed char*)(wsb + 3735552);  // same
  signed char* vwsT = (signed char*)(wsb + 5308416);  // same, [bh,d,n]
  signed char* ows  = (signed char*)(wsb + 6881280);  // 4096*384      = 1,572,864 B
  float*       E2   = (float*)(wsb + 8454144);        // 256*256 f32   =   262,144 B
  // total ws usage: 8,716,288 bytes

  quant16<<<384, 256, 0, stream>>>(x, xq, a_qkv_a, 98304);
  quant16<<<108, 256, 0, stream>>>(w_qkv, wqq, a_qkv_w, 27648);
  quant16<<<36, 256, 0, stream>>>(w_proj, wpq, a_proj_w, 9216);
  exp_table<<<256, 256, 0, stream>>>(E2, a_attn);
  gemm_qkv<<<dim3(32, 9), 256, 0, stream>>>(xq, wqq, qws, kws, vwsT,
                                            a_qkv_a, a_qkv_w, a_q, a_k, a_v);
  attn_fused<<<dim3(128, 12), 256, 0, stream>>>(qws, kws, vwsT, E2, ows,
                                                a_q, a_k, a_attn, a_attn2,
                                                a_v, a_proj_a);
  gemm_proj<<<dim3(64, 6), 256, 0, stream>>>(ows, wpq, b_proj, (float*)d_out,
                                             a_proj_a, a_proj_w);
}

// Round 7
// 167.381 us; speedup vs baseline: 2.7955x; 1.1045x over previous
//
#include <hip/hip_runtime.h>
#include <math.h>

// B=2, N=2048, C=384, H=6, D=64.  All quantized tensors hold INTEGER values
// (round(clip(x/a))) stored as int8; alpha scales are factored into epilogues.
// All GEMMs use v_mfma_i32_16x16x64_i8 (i32 accumulation exact; sums < 2^24
// so the (float) conversion is bit-exact).
//
// Round 7:
//  - phase-B score requant divide -> rcp + 2-FMA Newton (Markstein) sequence:
//    correctly rounded except rare 1-ulp cases, which the int8 quant lattice
//    snaps away (same error class as the integer-factoring we already use).
//  - P-LUT stored as int32 entries, row stride 257, overlaid on the
//    wave-private Ef rows: E1 gather bank = (row + s) % 32 -> ~2-way (free)
//    instead of 16-way pileup on score clusters.
//  - quant16 x3 + exp_table merged into one `prep` kernel.

typedef int i32x4 __attribute__((ext_vector_type(4)));

#define MFMA_I8(a, b, c) __builtin_amdgcn_mfma_i32_16x16x64_i8(a, b, c, 0, 0, 0)

__device__ __forceinline__ float qclip(float s) {
  return fminf(fmaxf(s, -128.0f), 127.0f);
}

// Markstein: correctly-rounded fp32 divide in all but ~1-ulp corner cases.
__device__ __forceinline__ float fdivn(float x, float c, float rc) {
  float q0 = x * rc;
  float e = fmaf(-c, q0, x);
  return fmaf(e, rc, q0);
}

__device__ __forceinline__ void quant16_body(const float* __restrict__ in,
                                             signed char* __restrict__ out,
                                             float a, int i) {
  const float4* p = (const float4*)in + 4 * (size_t)i;
  union { uint4 u; signed char c[16]; } o;
#pragma unroll
  for (int u = 0; u < 4; ++u) {
    float4 v = p[u];
    o.c[4 * u + 0] = (signed char)(int)rintf(qclip(v.x / a));
    o.c[4 * u + 1] = (signed char)(int)rintf(qclip(v.y / a));
    o.c[4 * u + 2] = (signed char)(int)rintf(qclip(v.z / a));
    o.c[4 * u + 3] = (signed char)(int)rintf(qclip(v.w / a));
  }
  *(uint4*)(out + 16 * (size_t)i) = o.u;
}

// ---------------- fused prep: quantize x, w_qkv, w_proj + exp table ----------------
__global__ __launch_bounds__(256)
void prep(const float* __restrict__ x, const float* __restrict__ wqkv,
          const float* __restrict__ wproj,
          signed char* __restrict__ xq, signed char* __restrict__ wqq,
          signed char* __restrict__ wpq, float* __restrict__ E2,
          const float* __restrict__ a_qkv_a, const float* __restrict__ a_qkv_w,
          const float* __restrict__ a_proj_w, const float* __restrict__ aattn) {
  const int b = blockIdx.x, t = threadIdx.x;
  if (b < 384) {
    int i = b * 256 + t;
    if (i < 98304) quant16_body(x, xq, a_qkv_a[0], i);
  } else if (b < 492) {
    int i = (b - 384) * 256 + t;
    if (i < 27648) quant16_body(wqkv, wqq, a_qkv_w[0], i);
  } else if (b < 528) {
    int i = (b - 492) * 256 + t;
    if (i < 9216) quant16_body(wproj, wpq, a_proj_w[0], i);
  } else {
    int i = (b - 528) * 256 + t;       // 0..65535
    float a = aattn[0];
    int vm = (i >> 8) - 128;
    int s = (i & 255) - 128;
    float m = a * (float)vm;
    E2[i] = expf(a * (float)s - m);    // same source expr as verified path
  }
}

// ---------------- QKV GEMM (i8 MFMA): [4096,384] @ [1152,384]^T ----------------
__global__ __launch_bounds__(256)
void gemm_qkv(const signed char* __restrict__ A, const signed char* __restrict__ W,
              signed char* __restrict__ qws, signed char* __restrict__ kws,
              signed char* __restrict__ vwsT,
              const float* __restrict__ aa, const float* __restrict__ aw,
              const float* __restrict__ aq, const float* __restrict__ ak,
              const float* __restrict__ av) {
  const int t = threadIdx.x;
  const int w = t >> 6, lane = t & 63;
  const int lm = lane & 15, quad = lane >> 4;
  const int wm = w >> 1, wn = w & 1;
  const int m0 = blockIdx.x * 128 + wm * 64;
  const int n0 = blockIdx.y * 128 + wn * 64;
  i32x4 acc[4][4] = {};
  for (int k0 = 0; k0 < 384; k0 += 64) {
    i32x4 af[4], bf[4];
#pragma unroll
    for (int mt = 0; mt < 4; ++mt)
      af[mt] = *(const i32x4*)(A + (size_t)(m0 + mt * 16 + lm) * 384 + k0 + quad * 16);
#pragma unroll
    for (int nt = 0; nt < 4; ++nt)
      bf[nt] = *(const i32x4*)(W + (size_t)(n0 + nt * 16 + lm) * 384 + k0 + quad * 16);
#pragma unroll
    for (int mt = 0; mt < 4; ++mt)
#pragma unroll
      for (int nt = 0; nt < 4; ++nt)
        acc[mt][nt] = MFMA_I8(af[mt], bf[nt], acc[mt][nt]);
  }
  const float sAB = aa[0] * aw[0];
  const float vaq = aq[0], vak = ak[0], vav = av[0];
#pragma unroll
  for (int mt = 0; mt < 4; ++mt) {
#pragma unroll
    for (int nt = 0; nt < 4; ++nt) {
      int cg = n0 + nt * 16 + lm;
      int t3 = cg / 384;
      int rem = cg - t3 * 384;
      int h = rem >> 6, d = rem & 63;
#pragma unroll
      for (int r = 0; r < 4; ++r) {
        int m = m0 + mt * 16 + quad * 4 + r;
        int bb = m >> 11, nn = m & 2047;
        int bh = bb * 6 + h;
        float val = (float)acc[mt][nt][r] * sAB;
        if (t3 == 0) {
          qws[((size_t)(bh * 2048 + nn) << 6) + d] = (signed char)(int)rintf(qclip(val / vaq));
        } else if (t3 == 1) {
          kws[((size_t)(bh * 2048 + nn) << 6) + d] = (signed char)(int)rintf(qclip(val / vak));
        } else {
          vwsT[((size_t)((bh << 6) + d) << 11) + nn] = (signed char)(int)rintf(qclip(val / vav));
        }
      }
    }
  }
}

// ---------------- fully fused attention: S = qK^T -> softmax -> PV ----------------
// Block = 256 thr = 4 waves, 16 q-rows, one bh.
#define TROW 2064
__global__ __launch_bounds__(256)
void attn_fused(const signed char* __restrict__ qws, const signed char* __restrict__ kws,
                const signed char* __restrict__ vwsT, const float* __restrict__ E2,
                signed char* __restrict__ ows,
                const float* __restrict__ aq, const float* __restrict__ ak,
                const float* __restrict__ aattn, const float* __restrict__ aattn2,
                const float* __restrict__ av, const float* __restrict__ apa) {
  __shared__ signed char tileS[16 * TROW];   // 33,024 B (int reduce aliases)
  __shared__ float EfS[16 * 257];            // 16,448 B; int LUT overlays per-row
  const int t = threadIdx.x;
  const int w = t >> 6, lane = t & 63;
  const int lm = lane & 15, quad = lane >> 4;
  const int i0 = blockIdx.x * 16;
  const int bh = blockIdx.y;

  const signed char* Qb = qws + ((size_t)bh << 17);
  const signed char* Kb = kws + ((size_t)bh << 17);

  // ---- phase B: scores tile.  bq = this block's 16 q-rows (B operand).
  i32x4 bq = *(const i32x4*)(Qb + ((size_t)(i0 + lm) << 6) + quad * 16);
  const float sc = aq[0] * ak[0] * 0.125f;
  const float ia = aattn[0];
  const float ria = 1.0f / ia;
#pragma unroll 4
  for (int ct = 0; ct < 32; ++ct) {
    int col0 = (w << 9) + ct * 16;
    i32x4 akf = *(const i32x4*)(Kb + ((size_t)(col0 + lm) << 6) + quad * 16);
    i32x4 z = {};
    i32x4 acc = MFMA_I8(akf, bq, z);
    union { unsigned int u; signed char c[4]; } pk;
#pragma unroll
    for (int r = 0; r < 4; ++r) {
      float sv = (float)acc[r] * sc;
      pk.c[r] = (signed char)(int)rintf(qclip(fdivn(sv, ia, ria)));
    }
    *(unsigned int*)(tileS + lm * TROW + col0 + quad * 4) = pk.u;
  }
  __syncthreads();

  // ---- phase C: per-row stats, Ef staging, l-sum, int32 LUT overlay.
  // Wave w owns rows 4w..4w+3 exclusively (reads and overwrites only them).
  const float a2 = aattn2[0];
  int* lutI = (int*)EfS;
#pragma unroll
  for (int rr = 0; rr < 4; ++rr) {
    const int row = w * 4 + rr;
    const char4* prow = (const char4*)(tileS + row * TROW);
    char4 vals[8];
    int vmax = -129;
#pragma unroll
    for (int u = 0; u < 8; ++u) {
      vals[u] = prow[lane + (u << 6)];
      vmax = max(vmax, (int)vals[u].x);
      vmax = max(vmax, (int)vals[u].y);
      vmax = max(vmax, (int)vals[u].z);
      vmax = max(vmax, (int)vals[u].w);
    }
#pragma unroll
    for (int off = 32; off > 0; off >>= 1)
      vmax = max(vmax, __shfl_xor(vmax, off, 64));
    // stage this row's exp slice: lane holds entries u*64+lane
    float efu[4];
#pragma unroll
    for (int u = 0; u < 4; ++u) {
      efu[u] = E2[((vmax + 128) << 8) + u * 64 + lane];
      EfS[row * 257 + u * 64 + lane] = efu[u];
    }
    const float* Er = EfS + row * 257 + 128;
    float l = 0.0f;
#pragma unroll
    for (int u = 0; u < 8; ++u) {
      l += Er[(int)vals[u].x];
      l += Er[(int)vals[u].y];
      l += Er[(int)vals[u].z];
      l += Er[(int)vals[u].w];
    }
#pragma unroll
    for (int off = 32; off > 0; off >>= 1)
      l += __shfl_xor(l, off, 64);
    // overwrite this row's Ef floats with the int LUT (wave-private rows;
    // DS ops from one wave complete in order, and these writes depend on l)
#pragma unroll
    for (int u = 0; u < 4; ++u) {
      int pq = (int)(signed char)(int)rintf(qclip(efu[u] / l / a2));
      lutI[row * 257 + u * 64 + lane] = pq;
    }
  }
  __syncthreads();

  // ---- phase E1: build this lane's A-fragments through the int LUT.
  // bank = (lm*257 + 128 + s) % 32 = (lm + s) % 32 -> spread by row.
  i32x4 areg[8];
  {
    const int* lr = lutI + lm * 257 + 128;
    const signed char* srow = tileS + lm * TROW + (w << 9) + quad * 16;
#pragma unroll
    for (int js = 0; js < 8; ++js) {
      union { uint4 u; signed char c[16]; } sv;
      sv.u = *(const uint4*)(srow + js * 64);
      union { i32x4 v; signed char c[16]; } dv;
#pragma unroll
      for (int b = 0; b < 16; ++b) dv.c[b] = (signed char)lr[(int)sv.c[b]];
      areg[js] = dv.v;
    }
  }

  // ---- phase E2: K-split GEMM, wave w sums K quarter [w*512,(w+1)*512)
  const signed char* Vb = vwsT + ((size_t)bh << 17) + (w << 9);
  i32x4 acc[4] = {};
#pragma unroll
  for (int js = 0; js < 8; ++js) {
    int j0 = js * 64;
    i32x4 bf[4];
#pragma unroll
    for (int nt = 0; nt < 4; ++nt)
      bf[nt] = *(const i32x4*)(Vb + ((size_t)(nt * 16 + lm) << 11) + j0 + quad * 16);
#pragma unroll
    for (int nt = 0; nt < 4; ++nt)
      acc[nt] = MFMA_I8(areg[js], bf[nt], acc[nt]);
  }

  // ---- phase F: exact integer reduce (aliases tile) + epilogue
  int* red = (int*)tileS;
  __syncthreads();
  if (w > 0) {
    int* rw = red + (w - 1) * 1088 + lane * 17;
#pragma unroll
    for (int nt = 0; nt < 4; ++nt)
#pragma unroll
      for (int r = 0; r < 4; ++r)
        rw[nt * 4 + r] = acc[nt][r];
  }
  __syncthreads();
  if (w == 0) {
    const float so = a2 * av[0];
    const float ipa = apa[0];
    int bb = bh / 6, h = bh % 6;
#pragma unroll
    for (int nt = 0; nt < 4; ++nt) {
      int d = nt * 16 + lm;
#pragma unroll
      for (int r = 0; r < 4; ++r) {
        int s = acc[nt][r] + red[lane * 17 + nt * 4 + r]
              + red[1088 + lane * 17 + nt * 4 + r]
              + red[2176 + lane * 17 + nt * 4 + r];
        int i = i0 + quad * 4 + r;
        ows[(size_t)((bb << 11) + i) * 384 + (h << 6) + d] =
            (signed char)(int)rintf(qclip((float)s * so / ipa));
      }
    }
  }
}

// ---------------- proj (i8 MFMA): [4096,384] @ [384,384]^T * s + bias ----------------
__global__ __launch_bounds__(256)
void gemm_proj(const signed char* __restrict__ A, const signed char* __restrict__ W,
               const float* __restrict__ bias, float* __restrict__ out,
               const float* __restrict__ apa, const float* __restrict__ apw) {
  const int t = threadIdx.x;
  const int w = t >> 6, lane = t & 63;
  const int lm = lane & 15, quad = lane >> 4;
  const int wm = w >> 1, wn = w & 1;
  const int m0 = blockIdx.x * 64 + wm * 32;
  const int n0 = blockIdx.y * 64 + wn * 32;
  i32x4 acc[2][2] = {};
  for (int k0 = 0; k0 < 384; k0 += 64) {
    i32x4 af[2], bf[2];
#pragma unroll
    for (int mt = 0; mt < 2; ++mt)
      af[mt] = *(const i32x4*)(A + (size_t)(m0 + mt * 16 + lm) * 384 + k0 + quad * 16);
#pragma unroll
    for (int nt = 0; nt < 2; ++nt)
      bf[nt] = *(const i32x4*)(W + (size_t)(n0 + nt * 16 + lm) * 384 + k0 + quad * 16);
#pragma unroll
    for (int mt = 0; mt < 2; ++mt)
#pragma unroll
      for (int nt = 0; nt < 2; ++nt)
        acc[mt][nt] = MFMA_I8(af[mt], bf[nt], acc[mt][nt]);
  }
  const float sAB = apa[0] * apw[0];
#pragma unroll
  for (int mt = 0; mt < 2; ++mt) {
#pragma unroll
    for (int nt = 0; nt < 2; ++nt) {
      int cg = n0 + nt * 16 + lm;
#pragma unroll
      for (int r = 0; r < 4; ++r) {
        int m = m0 + mt * 16 + quad * 4 + r;
        out[(size_t)m * 384 + cg] = (float)acc[mt][nt][r] * sAB + bias[cg];
      }
    }
  }
}

extern "C" void kernel_launch(void* const* d_in, const int* in_sizes, int n_in,
                              void* d_out, int out_size, void* d_ws, size_t ws_size,
                              hipStream_t stream) {
  const float* x        = (const float*)d_in[0];
  const float* w_qkv    = (const float*)d_in[1];
  const float* w_proj   = (const float*)d_in[2];
  const float* b_proj   = (const float*)d_in[3];
  const float* a_qkv_w  = (const float*)d_in[4];
  const float* a_qkv_a  = (const float*)d_in[5];
  const float* a_proj_w = (const float*)d_in[6];
  const float* a_proj_a = (const float*)d_in[7];
  const float* a_q      = (const float*)d_in[8];
  const float* a_k      = (const float*)d_in[9];
  const float* a_v      = (const float*)d_in[10];
  const float* a_attn   = (const float*)d_in[11];
  const float* a_attn2  = (const float*)d_in[12];

  char* wsb = (char*)d_ws;
  signed char* xq   = (signed char*)(wsb + 0);        // 4096*384      = 1,572,864 B
  signed char* wqq  = (signed char*)(wsb + 1572864);  // 1152*384      =   442,368 B
  signed char* wpq  = (signed char*)(wsb + 2015232);  //  384*384      =   147,456 B
  signed char* qws  = (signed char*)(wsb + 2162688);  // 12*2048*64    = 1,572,864 B
  signed char* kws  = (signed char*)(wsb + 3735552);  // same
  signed char* vwsT = (signed char*)(wsb + 5308416);  // same, [bh,d,n]
  signed char* ows  = (signed char*)(wsb + 6881280);  // 4096*384      = 1,572,864 B
  float*       E2   = (float*)(wsb + 8454144);        // 256*256 f32   =   262,144 B
  // total ws usage: 8,716,288 bytes

  prep<<<784, 256, 0, stream>>>(x, w_qkv, w_proj, xq, wqq, wpq, E2,
                                a_qkv_a, a_qkv_w, a_proj_w, a_attn);
  gemm_qkv<<<dim3(32, 9), 256, 0, stream>>>(xq, wqq, qws, kws, vwsT,
                                            a_qkv_a, a_qkv_w, a_q, a_k, a_v);
  attn_fused<<<dim3(128, 12), 256, 0, stream>>>(qws, kws, vwsT, E2, ows,
                                                a_q, a_k, a_attn, a_attn2,
                                                a_v, a_proj_a);
  gemm_proj<<<dim3(64, 6), 256, 0, stream>>>(ows, wpq, b_proj, (float*)d_out,
                                             a_proj_a, a_proj_w);
}

// Round 8
// 158.074 us; speedup vs baseline: 2.9601x; 1.0589x over previous
//
#include <hip/hip_runtime.h>
#include <math.h>

// B=2, N=2048, C=384, H=6, D=64.  All quantized tensors hold INTEGER values
// (round(clip(x/a))) stored as int8; alpha scales are factored into epilogues.
// All GEMMs use v_mfma_i32_16x16x64_i8 (i32 accumulation exact; sums < 2^24
// so the (float) conversion is bit-exact).
//
// Round 8:
//  - attn_fused: per-element P translation moved INTO phase C, reusing the
//    exact ef floats already gathered for the row sum; translated bytes are
//    written back over the tile.  Phase D + phase E1's 128 LDS gathers/lane
//    are gone; phase E is plain ds_read_b128.  fdivn with an IEEE 1/c seed is
//    provably correctly rounded (Markstein), so every value is bit-identical
//    to the verified LUT path.  Barriers 5 -> 4.
//  - gemm_qkv: retiled 128x128 -> 64x64 blocks, grid (64,18)=1152 (4.5
//    blocks/CU vs 1.1), 2-way K-split x 2-way n-split per wave, exact int
//    LDS reduce (stride-33 banks), Markstein epilogue.
//  - prep / attn epilogue: Markstein divides (exact, same theorem).

typedef int i32x4 __attribute__((ext_vector_type(4)));

#define MFMA_I8(a, b, c) __builtin_amdgcn_mfma_i32_16x16x64_i8(a, b, c, 0, 0, 0)

__device__ __forceinline__ float qclip(float s) {
  return fminf(fmaxf(s, -128.0f), 127.0f);
}

// Markstein divide: with rc = RN(1/c) (IEEE), result == RN(x/c) for all
// normal inputs -> bit-identical to the / operator.
__device__ __forceinline__ float fdivn(float x, float c, float rc) {
  float q0 = x * rc;
  float e = fmaf(-c, q0, x);
  return fmaf(e, rc, q0);
}

__device__ __forceinline__ void quant16_body(const float* __restrict__ in,
                                             signed char* __restrict__ out,
                                             float a, int i) {
  const float ra = 1.0f / a;
  const float4* p = (const float4*)in + 4 * (size_t)i;
  union { uint4 u; signed char c[16]; } o;
#pragma unroll
  for (int u = 0; u < 4; ++u) {
    float4 v = p[u];
    o.c[4 * u + 0] = (signed char)(int)rintf(qclip(fdivn(v.x, a, ra)));
    o.c[4 * u + 1] = (signed char)(int)rintf(qclip(fdivn(v.y, a, ra)));
    o.c[4 * u + 2] = (signed char)(int)rintf(qclip(fdivn(v.z, a, ra)));
    o.c[4 * u + 3] = (signed char)(int)rintf(qclip(fdivn(v.w, a, ra)));
  }
  *(uint4*)(out + 16 * (size_t)i) = o.u;
}

// ---------------- fused prep: quantize x, w_qkv, w_proj + exp table ----------------
__global__ __launch_bounds__(256)
void prep(const float* __restrict__ x, const float* __restrict__ wqkv,
          const float* __restrict__ wproj,
          signed char* __restrict__ xq, signed char* __restrict__ wqq,
          signed char* __restrict__ wpq, float* __restrict__ E2,
          const float* __restrict__ a_qkv_a, const float* __restrict__ a_qkv_w,
          const float* __restrict__ a_proj_w, const float* __restrict__ aattn) {
  const int b = blockIdx.x, t = threadIdx.x;
  if (b < 384) {
    int i = b * 256 + t;
    if (i < 98304) quant16_body(x, xq, a_qkv_a[0], i);
  } else if (b < 492) {
    int i = (b - 384) * 256 + t;
    if (i < 27648) quant16_body(wqkv, wqq, a_qkv_w[0], i);
  } else if (b < 528) {
    int i = (b - 492) * 256 + t;
    if (i < 9216) quant16_body(wproj, wpq, a_proj_w[0], i);
  } else {
    int i = (b - 528) * 256 + t;       // 0..65535
    float a = aattn[0];
    int vm = (i >> 8) - 128;
    int s = (i & 255) - 128;
    float m = a * (float)vm;
    E2[i] = expf(a * (float)s - m);    // same source expr as verified path
  }
}

// ---------------- QKV GEMM (i8 MFMA): [4096,384] @ [1152,384]^T ----------------
// 64x64 block tile, grid (64,18).  Wave (kw,nw): kw = K-half (192), nw = n-half
// (32 cols).  Exact int K-reduce through LDS (stride 33), epilogue on kw=0.
__global__ __launch_bounds__(256)
void gemm_qkv(const signed char* __restrict__ A, const signed char* __restrict__ W,
              signed char* __restrict__ qws, signed char* __restrict__ kws,
              signed char* __restrict__ vwsT,
              const float* __restrict__ aa, const float* __restrict__ aw,
              const float* __restrict__ aq, const float* __restrict__ ak,
              const float* __restrict__ av) {
  __shared__ int red[2 * 64 * 33];     // 16,896 B
  const int t = threadIdx.x;
  const int w = t >> 6, lane = t & 63;
  const int lm = lane & 15, quad = lane >> 4;
  const int kw = w >> 1, nw = w & 1;
  const int m0 = blockIdx.x * 64;
  const int n0 = blockIdx.y * 64 + nw * 32;
  i32x4 acc[4][2] = {};
#pragma unroll
  for (int kk = 0; kk < 3; ++kk) {
    int k0 = kw * 192 + kk * 64;
    i32x4 af[4], bf[2];
#pragma unroll
    for (int mt = 0; mt < 4; ++mt)
      af[mt] = *(const i32x4*)(A + (size_t)(m0 + mt * 16 + lm) * 384 + k0 + quad * 16);
#pragma unroll
    for (int nt = 0; nt < 2; ++nt)
      bf[nt] = *(const i32x4*)(W + (size_t)(n0 + nt * 16 + lm) * 384 + k0 + quad * 16);
#pragma unroll
    for (int mt = 0; mt < 4; ++mt)
#pragma unroll
      for (int nt = 0; nt < 2; ++nt)
        acc[mt][nt] = MFMA_I8(af[mt], bf[nt], acc[mt][nt]);
  }
  if (kw == 1) {
    int* rw = red + nw * 2112 + lane * 33;
#pragma unroll
    for (int mt = 0; mt < 4; ++mt)
#pragma unroll
      for (int nt = 0; nt < 2; ++nt)
#pragma unroll
        for (int r = 0; r < 4; ++r)
          rw[mt * 8 + nt * 4 + r] = acc[mt][nt][r];
  }
  __syncthreads();
  if (kw == 0) {
    const int* rw = red + nw * 2112 + lane * 33;
    const float sAB = aa[0] * aw[0];
    const float vaq = aq[0], vak = ak[0], vav = av[0];
    const float rq = 1.0f / vaq, rk = 1.0f / vak, rv = 1.0f / vav;
#pragma unroll
    for (int mt = 0; mt < 4; ++mt) {
#pragma unroll
      for (int nt = 0; nt < 2; ++nt) {
        int cg = n0 + nt * 16 + lm;
        int t3 = cg / 384;
        int rem = cg - t3 * 384;
        int h = rem >> 6, d = rem & 63;
#pragma unroll
        for (int r = 0; r < 4; ++r) {
          int m = m0 + mt * 16 + quad * 4 + r;
          int bb = m >> 11, nn = m & 2047;
          int bh = bb * 6 + h;
          int sum = acc[mt][nt][r] + rw[mt * 8 + nt * 4 + r];
          float val = (float)sum * sAB;
          if (t3 == 0) {
            qws[((size_t)(bh * 2048 + nn) << 6) + d] =
                (signed char)(int)rintf(qclip(fdivn(val, vaq, rq)));
          } else if (t3 == 1) {
            kws[((size_t)(bh * 2048 + nn) << 6) + d] =
                (signed char)(int)rintf(qclip(fdivn(val, vak, rk)));
          } else {
            vwsT[((size_t)((bh << 6) + d) << 11) + nn] =
                (signed char)(int)rintf(qclip(fdivn(val, vav, rv)));
          }
        }
      }
    }
  }
}

// ---------------- fully fused attention: S = qK^T -> softmax -> PV ----------------
// Block = 256 thr = 4 waves, 16 q-rows, one bh.
// B: scores tile via operand-swapped MFMA, requant, ds_write_b32 (padded).
// C: per-row stats in the verified lane order; Ef slice staged to LDS; the
//    sum's gathered ef floats are REUSED to translate S->P per element
//    (exact Markstein divides == round-7 LUT values), written back in place.
// E: plain ds_read_b128 A-frags; 4-way K-split i8 GEMM, V from global.
// F: exact integer LDS reduce (aliases tile) + requant epilogue.
#define TROW 2064
__global__ __launch_bounds__(256)
void attn_fused(const signed char* __restrict__ qws, const signed char* __restrict__ kws,
                const signed char* __restrict__ vwsT, const float* __restrict__ E2,
                signed char* __restrict__ ows,
                const float* __restrict__ aq, const float* __restrict__ ak,
                const float* __restrict__ aattn, const float* __restrict__ aattn2,
                const float* __restrict__ av, const float* __restrict__ apa) {
  __shared__ signed char tileS[16 * TROW];   // 33,024 B (int reduce aliases)
  __shared__ float EfS[16 * 257];            // 16,448 B exp-slice staging
  const int t = threadIdx.x;
  const int w = t >> 6, lane = t & 63;
  const int lm = lane & 15, quad = lane >> 4;
  const int i0 = blockIdx.x * 16;
  const int bh = blockIdx.y;

  const signed char* Qb = qws + ((size_t)bh << 17);
  const signed char* Kb = kws + ((size_t)bh << 17);

  // ---- phase B: scores tile.  bq = this block's 16 q-rows (B operand).
  i32x4 bq = *(const i32x4*)(Qb + ((size_t)(i0 + lm) << 6) + quad * 16);
  const float sc = aq[0] * ak[0] * 0.125f;
  const float ia = aattn[0];
  const float ria = 1.0f / ia;
#pragma unroll 4
  for (int ct = 0; ct < 32; ++ct) {
    int col0 = (w << 9) + ct * 16;
    i32x4 akf = *(const i32x4*)(Kb + ((size_t)(col0 + lm) << 6) + quad * 16);
    i32x4 z = {};
    i32x4 acc = MFMA_I8(akf, bq, z);
    union { unsigned int u; signed char c[4]; } pk;
#pragma unroll
    for (int r = 0; r < 4; ++r) {
      float sv = (float)acc[r] * sc;
      pk.c[r] = (signed char)(int)rintf(qclip(fdivn(sv, ia, ria)));
    }
    *(unsigned int*)(tileS + lm * TROW + col0 + quad * 4) = pk.u;
  }
  __syncthreads();

  // ---- phase C: stats + in-place S->P translation (wave w owns rows 4w..4w+3)
  const float a2 = aattn2[0];
  const float ra2 = 1.0f / a2;
#pragma unroll
  for (int rr = 0; rr < 4; ++rr) {
    const int row = w * 4 + rr;
    char4* prow = (char4*)(tileS + row * TROW);
    char4 vals[8];
    int vmax = -129;
#pragma unroll
    for (int u = 0; u < 8; ++u) {
      vals[u] = prow[lane + (u << 6)];
      vmax = max(vmax, (int)vals[u].x);
      vmax = max(vmax, (int)vals[u].y);
      vmax = max(vmax, (int)vals[u].z);
      vmax = max(vmax, (int)vals[u].w);
    }
#pragma unroll
    for (int off = 32; off > 0; off >>= 1)
      vmax = max(vmax, __shfl_xor(vmax, off, 64));
    // stage this row's exp slice: lane holds entries u*64+lane
#pragma unroll
    for (int u = 0; u < 4; ++u)
      EfS[row * 257 + u * 64 + lane] = E2[((vmax + 128) << 8) + u * 64 + lane];
    const float* Er = EfS + row * 257 + 128;
    // gather ef for every element (kept for translation) and sum in the
    // verified order
    float ge[8][4];
    float l = 0.0f;
#pragma unroll
    for (int u = 0; u < 8; ++u) {
      ge[u][0] = Er[(int)vals[u].x];
      ge[u][1] = Er[(int)vals[u].y];
      ge[u][2] = Er[(int)vals[u].z];
      ge[u][3] = Er[(int)vals[u].w];
      l += ge[u][0];
      l += ge[u][1];
      l += ge[u][2];
      l += ge[u][3];
    }
#pragma unroll
    for (int off = 32; off > 0; off >>= 1)
      l += __shfl_xor(l, off, 64);
    // translate: p = rint(clip(ef/l/a2)), exact (Markstein with IEEE seeds)
    const float rl = 1.0f / l;
#pragma unroll
    for (int u = 0; u < 8; ++u) {
      union { unsigned int ui; signed char c[4]; } pk;
#pragma unroll
      for (int c = 0; c < 4; ++c) {
        float tq = fdivn(ge[u][c], l, rl);
        pk.c[c] = (signed char)(int)rintf(qclip(fdivn(tq, a2, ra2)));
      }
      *(unsigned int*)(prow + lane + (u << 6)) = pk.ui;
    }
  }
  __syncthreads();

  // ---- phase E: plain A-frag reads + K-split GEMM (wave w: K quarter)
  i32x4 areg[8];
  {
    const signed char* srow = tileS + lm * TROW + (w << 9) + quad * 16;
#pragma unroll
    for (int js = 0; js < 8; ++js)
      areg[js] = *(const i32x4*)(srow + js * 64);
  }
  const signed char* Vb = vwsT + ((size_t)bh << 17) + (w << 9);
  i32x4 acc[4] = {};
#pragma unroll
  for (int js = 0; js < 8; ++js) {
    int j0 = js * 64;
    i32x4 bf[4];
#pragma unroll
    for (int nt = 0; nt < 4; ++nt)
      bf[nt] = *(const i32x4*)(Vb + ((size_t)(nt * 16 + lm) << 11) + j0 + quad * 16);
#pragma unroll
    for (int nt = 0; nt < 4; ++nt)
      acc[nt] = MFMA_I8(areg[js], bf[nt], acc[nt]);
  }

  // ---- phase F: exact integer reduce (aliases tile) + epilogue
  int* red = (int*)tileS;
  __syncthreads();
  if (w > 0) {
    int* rw = red + (w - 1) * 1088 + lane * 17;
#pragma unroll
    for (int nt = 0; nt < 4; ++nt)
#pragma unroll
      for (int r = 0; r < 4; ++r)
        rw[nt * 4 + r] = acc[nt][r];
  }
  __syncthreads();
  if (w == 0) {
    const float so = a2 * av[0];
    const float ipa = apa[0];
    const float ripa = 1.0f / ipa;
    int bb = bh / 6, h = bh % 6;
#pragma unroll
    for (int nt = 0; nt < 4; ++nt) {
      int d = nt * 16 + lm;
#pragma unroll
      for (int r = 0; r < 4; ++r) {
        int s = acc[nt][r] + red[lane * 17 + nt * 4 + r]
              + red[1088 + lane * 17 + nt * 4 + r]
              + red[2176 + lane * 17 + nt * 4 + r];
        int i = i0 + quad * 4 + r;
        ows[(size_t)((bb << 11) + i) * 384 + (h << 6) + d] =
            (signed char)(int)rintf(qclip(fdivn((float)s * so, ipa, ripa)));
      }
    }
  }
}

// ---------------- proj (i8 MFMA): [4096,384] @ [384,384]^T * s + bias ----------------
__global__ __launch_bounds__(256)
void gemm_proj(const signed char* __restrict__ A, const signed char* __restrict__ W,
               const float* __restrict__ bias, float* __restrict__ out,
               const float* __restrict__ apa, const float* __restrict__ apw) {
  const int t = threadIdx.x;
  const int w = t >> 6, lane = t & 63;
  const int lm = lane & 15, quad = lane >> 4;
  const int wm = w >> 1, wn = w & 1;
  const int m0 = blockIdx.x * 64 + wm * 32;
  const int n0 = blockIdx.y * 64 + wn * 32;
  i32x4 acc[2][2] = {};
  for (int k0 = 0; k0 < 384; k0 += 64) {
    i32x4 af[2], bf[2];
#pragma unroll
    for (int mt = 0; mt < 2; ++mt)
      af[mt] = *(const i32x4*)(A + (size_t)(m0 + mt * 16 + lm) * 384 + k0 + quad * 16);
#pragma unroll
    for (int nt = 0; nt < 2; ++nt)
      bf[nt] = *(const i32x4*)(W + (size_t)(n0 + nt * 16 + lm) * 384 + k0 + quad * 16);
#pragma unroll
    for (int mt = 0; mt < 2; ++mt)
#pragma unroll
      for (int nt = 0; nt < 2; ++nt)
        acc[mt][nt] = MFMA_I8(af[mt], bf[nt], acc[mt][nt]);
  }
  const float sAB = apa[0] * apw[0];
#pragma unroll
  for (int mt = 0; mt < 2; ++mt) {
#pragma unroll
    for (int nt = 0; nt < 2; ++nt) {
      int cg = n0 + nt * 16 + lm;
#pragma unroll
      for (int r = 0; r < 4; ++r) {
        int m = m0 + mt * 16 + quad * 4 + r;
        out[(size_t)m * 384 + cg] = (float)acc[mt][nt][r] * sAB + bias[cg];
      }
    }
  }
}

extern "C" void kernel_launch(void* const* d_in, const int* in_sizes, int n_in,
                              void* d_out, int out_size, void* d_ws, size_t ws_size,
                              hipStream_t stream) {
  const float* x        = (const float*)d_in[0];
  const float* w_qkv    = (const float*)d_in[1];
  const float* w_proj   = (const float*)d_in[2];
  const float* b_proj   = (const float*)d_in[3];
  const float* a_qkv_w  = (const float*)d_in[4];
  const float* a_qkv_a  = (const float*)d_in[5];
  const float* a_proj_w = (const float*)d_in[6];
  const float* a_proj_a = (const float*)d_in[7];
  const float* a_q      = (const float*)d_in[8];
  const float* a_k      = (const float*)d_in[9];
  const float* a_v      = (const float*)d_in[10];
  const float* a_attn   = (const float*)d_in[11];
  const float* a_attn2  = (const float*)d_in[12];

  char* wsb = (char*)d_ws;
  signed char* xq   = (signed char*)(wsb + 0);        // 4096*384      = 1,572,864 B
  signed char* wqq  = (signed char*)(wsb + 1572864);  // 1152*384      =   442,368 B
  signed char* wpq  = (signed char*)(wsb + 2015232);  //  384*384      =   147,456 B
  signed char* qws  = (signed char*)(wsb + 2162688);  // 12*2048*64    = 1,572,864 B
  signed char* kws  = (signed char*)(wsb + 3735552);  // same
  signed char* vwsT = (signed char*)(wsb + 5308416);  // same, [bh,d,n]
  signed char* ows  = (signed char*)(wsb + 6881280);  // 4096*384      = 1,572,864 B
  float*       E2   = (float*)(wsb + 8454144);        // 256*256 f32   =   262,144 B
  // total ws usage: 8,716,288 bytes

  prep<<<784, 256, 0, stream>>>(x, w_qkv, w_proj, xq, wqq, wpq, E2,
                                a_qkv_a, a_qkv_w, a_proj_w, a_attn);
  gemm_qkv<<<dim3(64, 18), 256, 0, stream>>>(xq, wqq, qws, kws, vwsT,
                                             a_qkv_a, a_qkv_w, a_q, a_k, a_v);
  attn_fused<<<dim3(128, 12), 256, 0, stream>>>(qws, kws, vwsT, E2, ows,
                                                a_q, a_k, a_attn, a_attn2,
                                                a_v, a_proj_a);
  gemm_proj<<<dim3(64, 6), 256, 0, stream>>>(ows, wpq, b_proj, (float*)d_out,
                                             a_proj_a, a_proj_w);
}

// Round 9
// 153.359 us; speedup vs baseline: 3.0511x; 1.0307x over previous
//
#include <hip/hip_runtime.h>
#include <math.h>

// B=2, N=2048, C=384, H=6, D=64.  All quantized tensors hold INTEGER values
// (round(clip(x/a))) stored as int8; alpha scales are factored into epilogues.
// All GEMMs use v_mfma_i32_16x16x64_i8 (i32 accumulation exact; sums < 2^24
// so the (float) conversion is bit-exact).
//
// Round 9:
//  - attn_fused LDS cut 49.7KB -> 37.1KB: Ef staging is 4 wave-private slots
//    (each wave only uses one row slice at a time) -> 4 blocks/CU (was 3).
//  - phase-B requant and phase-C translate packed into float2 ext-vector ops
//    with __builtin_elementwise_fma -> v_pk_{mul,fma}_f32.  Per-lane IEEE ops
//    and order unchanged -> bit-identical (absmax 0.0 preserved).
//  - row sum remains a scalar ordered chain (bit-exact l).

typedef int i32x4 __attribute__((ext_vector_type(4)));
typedef float f32x2 __attribute__((ext_vector_type(2)));

#define MFMA_I8(a, b, c) __builtin_amdgcn_mfma_i32_16x16x64_i8(a, b, c, 0, 0, 0)

__device__ __forceinline__ float qclip(float s) {
  return fminf(fmaxf(s, -128.0f), 127.0f);
}

// Markstein divide: with rc = RN(1/c) (IEEE), result == RN(x/c) for all
// normal inputs -> bit-identical to the / operator.
__device__ __forceinline__ float fdivn(float x, float c, float rc) {
  float q0 = x * rc;
  float e = fmaf(-c, q0, x);
  return fmaf(e, rc, q0);
}

// Packed pair version: identical per-lane ops/order -> bit-identical.
__device__ __forceinline__ f32x2 fdivn2(f32x2 x, f32x2 c, f32x2 rc) {
  f32x2 q0 = x * rc;
  f32x2 e = __builtin_elementwise_fma(-c, q0, x);
  return __builtin_elementwise_fma(e, rc, q0);
}

__device__ __forceinline__ void quant16_body(const float* __restrict__ in,
                                             signed char* __restrict__ out,
                                             float a, int i) {
  const float ra = 1.0f / a;
  const float4* p = (const float4*)in + 4 * (size_t)i;
  union { uint4 u; signed char c[16]; } o;
#pragma unroll
  for (int u = 0; u < 4; ++u) {
    float4 v = p[u];
    o.c[4 * u + 0] = (signed char)(int)rintf(qclip(fdivn(v.x, a, ra)));
    o.c[4 * u + 1] = (signed char)(int)rintf(qclip(fdivn(v.y, a, ra)));
    o.c[4 * u + 2] = (signed char)(int)rintf(qclip(fdivn(v.z, a, ra)));
    o.c[4 * u + 3] = (signed char)(int)rintf(qclip(fdivn(v.w, a, ra)));
  }
  *(uint4*)(out + 16 * (size_t)i) = o.u;
}

// ---------------- fused prep: quantize x, w_qkv, w_proj + exp table ----------------
__global__ __launch_bounds__(256)
void prep(const float* __restrict__ x, const float* __restrict__ wqkv,
          const float* __restrict__ wproj,
          signed char* __restrict__ xq, signed char* __restrict__ wqq,
          signed char* __restrict__ wpq, float* __restrict__ E2,
          const float* __restrict__ a_qkv_a, const float* __restrict__ a_qkv_w,
          const float* __restrict__ a_proj_w, const float* __restrict__ aattn) {
  const int b = blockIdx.x, t = threadIdx.x;
  if (b < 384) {
    int i = b * 256 + t;
    if (i < 98304) quant16_body(x, xq, a_qkv_a[0], i);
  } else if (b < 492) {
    int i = (b - 384) * 256 + t;
    if (i < 27648) quant16_body(wqkv, wqq, a_qkv_w[0], i);
  } else if (b < 528) {
    int i = (b - 492) * 256 + t;
    if (i < 9216) quant16_body(wproj, wpq, a_proj_w[0], i);
  } else {
    int i = (b - 528) * 256 + t;       // 0..65535
    float a = aattn[0];
    int vm = (i >> 8) - 128;
    int s = (i & 255) - 128;
    float m = a * (float)vm;
    E2[i] = expf(a * (float)s - m);    // same source expr as verified path
  }
}

// ---------------- QKV GEMM (i8 MFMA): [4096,384] @ [1152,384]^T ----------------
// 64x64 block tile, grid (64,18).  Wave (kw,nw): kw = K-half (192), nw = n-half
// (32 cols).  Exact int K-reduce through LDS (stride 33), epilogue on kw=0.
__global__ __launch_bounds__(256)
void gemm_qkv(const signed char* __restrict__ A, const signed char* __restrict__ W,
              signed char* __restrict__ qws, signed char* __restrict__ kws,
              signed char* __restrict__ vwsT,
              const float* __restrict__ aa, const float* __restrict__ aw,
              const float* __restrict__ aq, const float* __restrict__ ak,
              const float* __restrict__ av) {
  __shared__ int red[2 * 64 * 33];     // 16,896 B
  const int t = threadIdx.x;
  const int w = t >> 6, lane = t & 63;
  const int lm = lane & 15, quad = lane >> 4;
  const int kw = w >> 1, nw = w & 1;
  const int m0 = blockIdx.x * 64;
  const int n0 = blockIdx.y * 64 + nw * 32;
  i32x4 acc[4][2] = {};
#pragma unroll
  for (int kk = 0; kk < 3; ++kk) {
    int k0 = kw * 192 + kk * 64;
    i32x4 af[4], bf[2];
#pragma unroll
    for (int mt = 0; mt < 4; ++mt)
      af[mt] = *(const i32x4*)(A + (size_t)(m0 + mt * 16 + lm) * 384 + k0 + quad * 16);
#pragma unroll
    for (int nt = 0; nt < 2; ++nt)
      bf[nt] = *(const i32x4*)(W + (size_t)(n0 + nt * 16 + lm) * 384 + k0 + quad * 16);
#pragma unroll
    for (int mt = 0; mt < 4; ++mt)
#pragma unroll
      for (int nt = 0; nt < 2; ++nt)
        acc[mt][nt] = MFMA_I8(af[mt], bf[nt], acc[mt][nt]);
  }
  if (kw == 1) {
    int* rw = red + nw * 2112 + lane * 33;
#pragma unroll
    for (int mt = 0; mt < 4; ++mt)
#pragma unroll
      for (int nt = 0; nt < 2; ++nt)
#pragma unroll
        for (int r = 0; r < 4; ++r)
          rw[mt * 8 + nt * 4 + r] = acc[mt][nt][r];
  }
  __syncthreads();
  if (kw == 0) {
    const int* rw = red + nw * 2112 + lane * 33;
    const float sAB = aa[0] * aw[0];
    const float vaq = aq[0], vak = ak[0], vav = av[0];
    const float rq = 1.0f / vaq, rk = 1.0f / vak, rv = 1.0f / vav;
#pragma unroll
    for (int mt = 0; mt < 4; ++mt) {
#pragma unroll
      for (int nt = 0; nt < 2; ++nt) {
        int cg = n0 + nt * 16 + lm;
        int t3 = cg / 384;
        int rem = cg - t3 * 384;
        int h = rem >> 6, d = rem & 63;
#pragma unroll
        for (int r = 0; r < 4; ++r) {
          int m = m0 + mt * 16 + quad * 4 + r;
          int bb = m >> 11, nn = m & 2047;
          int bh = bb * 6 + h;
          int sum = acc[mt][nt][r] + rw[mt * 8 + nt * 4 + r];
          float val = (float)sum * sAB;
          if (t3 == 0) {
            qws[((size_t)(bh * 2048 + nn) << 6) + d] =
                (signed char)(int)rintf(qclip(fdivn(val, vaq, rq)));
          } else if (t3 == 1) {
            kws[((size_t)(bh * 2048 + nn) << 6) + d] =
                (signed char)(int)rintf(qclip(fdivn(val, vak, rk)));
          } else {
            vwsT[((size_t)((bh << 6) + d) << 11) + nn] =
                (signed char)(int)rintf(qclip(fdivn(val, vav, rv)));
          }
        }
      }
    }
  }
}

// ---------------- fully fused attention: S = qK^T -> softmax -> PV ----------------
// Block = 256 thr = 4 waves, 16 q-rows, one bh.
// B: scores tile via operand-swapped MFMA, packed-f32 requant, ds_write_b32.
// C: per-row stats (verified lane order); Ef slice staged to a WAVE-PRIVATE
//    LDS slot; gathered ef floats reused for packed-f32 in-place translation.
// E: plain ds_read_b128 A-frags; 4-way K-split i8 GEMM, V from global.
// F: exact integer LDS reduce (aliases tile) + requant epilogue.
#define TROW 2064
__global__ __launch_bounds__(256)
void attn_fused(const signed char* __restrict__ qws, const signed char* __restrict__ kws,
                const signed char* __restrict__ vwsT, const float* __restrict__ E2,
                signed char* __restrict__ ows,
                const float* __restrict__ aq, const float* __restrict__ ak,
                const float* __restrict__ aattn, const float* __restrict__ aattn2,
                const float* __restrict__ av, const float* __restrict__ apa) {
  __shared__ signed char tileS[16 * TROW];   // 33,024 B (int reduce aliases)
  __shared__ float EfS[4 * 257];             //  4,112 B wave-private slots
  const int t = threadIdx.x;
  const int w = t >> 6, lane = t & 63;
  const int lm = lane & 15, quad = lane >> 4;
  const int i0 = blockIdx.x * 16;
  const int bh = blockIdx.y;

  const signed char* Qb = qws + ((size_t)bh << 17);
  const signed char* Kb = kws + ((size_t)bh << 17);

  // ---- phase B: scores tile.  bq = this block's 16 q-rows (B operand).
  i32x4 bq = *(const i32x4*)(Qb + ((size_t)(i0 + lm) << 6) + quad * 16);
  const float sc = aq[0] * ak[0] * 0.125f;
  const float ia = aattn[0];
  const float ria = 1.0f / ia;
  const f32x2 ia2v = {ia, ia}, ria2v = {ria, ria}, sc2v = {sc, sc};
#pragma unroll 4
  for (int ct = 0; ct < 32; ++ct) {
    int col0 = (w << 9) + ct * 16;
    i32x4 akf = *(const i32x4*)(Kb + ((size_t)(col0 + lm) << 6) + quad * 16);
    i32x4 z = {};
    i32x4 acc = MFMA_I8(akf, bq, z);
    f32x2 sv01 = {(float)acc[0], (float)acc[1]};
    f32x2 sv23 = {(float)acc[2], (float)acc[3]};
    f32x2 q01 = fdivn2(sv01 * sc2v, ia2v, ria2v);
    f32x2 q23 = fdivn2(sv23 * sc2v, ia2v, ria2v);
    union { unsigned int u; signed char c[4]; } pk;
    pk.c[0] = (signed char)(int)rintf(qclip(q01.x));
    pk.c[1] = (signed char)(int)rintf(qclip(q01.y));
    pk.c[2] = (signed char)(int)rintf(qclip(q23.x));
    pk.c[3] = (signed char)(int)rintf(qclip(q23.y));
    *(unsigned int*)(tileS + lm * TROW + col0 + quad * 4) = pk.u;
  }
  __syncthreads();

  // ---- phase C: stats + in-place S->P translation (wave w owns rows 4w..4w+3)
  const float a2 = aattn2[0];
  const float ra2 = 1.0f / a2;
  const f32x2 a22v = {a2, a2}, ra22v = {ra2, ra2};
  float* Efw = EfS + w * 257;                // wave-private slot
#pragma unroll
  for (int rr = 0; rr < 4; ++rr) {
    const int row = w * 4 + rr;
    char4* prow = (char4*)(tileS + row * TROW);
    char4 vals[8];
    int vmax = -129;
#pragma unroll
    for (int u = 0; u < 8; ++u) {
      vals[u] = prow[lane + (u << 6)];
      vmax = max(vmax, (int)vals[u].x);
      vmax = max(vmax, (int)vals[u].y);
      vmax = max(vmax, (int)vals[u].z);
      vmax = max(vmax, (int)vals[u].w);
    }
#pragma unroll
    for (int off = 32; off > 0; off >>= 1)
      vmax = max(vmax, __shfl_xor(vmax, off, 64));
    // stage this row's exp slice into the wave slot: lane holds u*64+lane
#pragma unroll
    for (int u = 0; u < 4; ++u)
      Efw[u * 64 + lane] = E2[((vmax + 128) << 8) + u * 64 + lane];
    const float* Er = Efw + 128;
    // gather ef for every element (kept for translation) and sum in the
    // verified order (scalar dependent chain -> bit-exact l)
    float ge[8][4];
    float l = 0.0f;
#pragma unroll
    for (int u = 0; u < 8; ++u) {
      ge[u][0] = Er[(int)vals[u].x];
      ge[u][1] = Er[(int)vals[u].y];
      ge[u][2] = Er[(int)vals[u].z];
      ge[u][3] = Er[(int)vals[u].w];
      l += ge[u][0];
      l += ge[u][1];
      l += ge[u][2];
      l += ge[u][3];
    }
#pragma unroll
    for (int off = 32; off > 0; off >>= 1)
      l += __shfl_xor(l, off, 64);
    // translate: p = rint(clip(ef/l/a2)), exact Markstein, packed pairs
    const float rl = 1.0f / l;
    const f32x2 l2v = {l, l}, rl2v = {rl, rl};
#pragma unroll
    for (int u = 0; u < 8; ++u) {
      f32x2 g01 = {ge[u][0], ge[u][1]};
      f32x2 g23 = {ge[u][2], ge[u][3]};
      f32x2 t01 = fdivn2(fdivn2(g01, l2v, rl2v), a22v, ra22v);
      f32x2 t23 = fdivn2(fdivn2(g23, l2v, rl2v), a22v, ra22v);
      union { unsigned int ui; signed char c[4]; } pk;
      pk.c[0] = (signed char)(int)rintf(qclip(t01.x));
      pk.c[1] = (signed char)(int)rintf(qclip(t01.y));
      pk.c[2] = (signed char)(int)rintf(qclip(t23.x));
      pk.c[3] = (signed char)(int)rintf(qclip(t23.y));
      *(unsigned int*)(prow + lane + (u << 6)) = pk.ui;
    }
  }
  __syncthreads();

  // ---- phase E: plain A-frag reads + K-split GEMM (wave w: K quarter)
  i32x4 areg[8];
  {
    const signed char* srow = tileS + lm * TROW + (w << 9) + quad * 16;
#pragma unroll
    for (int js = 0; js < 8; ++js)
      areg[js] = *(const i32x4*)(srow + js * 64);
  }
  const signed char* Vb = vwsT + ((size_t)bh << 17) + (w << 9);
  i32x4 acc[4] = {};
#pragma unroll
  for (int js = 0; js < 8; ++js) {
    int j0 = js * 64;
    i32x4 bf[4];
#pragma unroll
    for (int nt = 0; nt < 4; ++nt)
      bf[nt] = *(const i32x4*)(Vb + ((size_t)(nt * 16 + lm) << 11) + j0 + quad * 16);
#pragma unroll
    for (int nt = 0; nt < 4; ++nt)
      acc[nt] = MFMA_I8(areg[js], bf[nt], acc[nt]);
  }

  // ---- phase F: exact integer reduce (aliases tile) + epilogue
  int* red = (int*)tileS;
  __syncthreads();
  if (w > 0) {
    int* rw = red + (w - 1) * 1088 + lane * 17;
#pragma unroll
    for (int nt = 0; nt < 4; ++nt)
#pragma unroll
      for (int r = 0; r < 4; ++r)
        rw[nt * 4 + r] = acc[nt][r];
  }
  __syncthreads();
  if (w == 0) {
    const float so = a2 * av[0];
    const float ipa = apa[0];
    const float ripa = 1.0f / ipa;
    int bb = bh / 6, h = bh % 6;
#pragma unroll
    for (int nt = 0; nt < 4; ++nt) {
      int d = nt * 16 + lm;
#pragma unroll
      for (int r = 0; r < 4; ++r) {
        int s = acc[nt][r] + red[lane * 17 + nt * 4 + r]
              + red[1088 + lane * 17 + nt * 4 + r]
              + red[2176 + lane * 17 + nt * 4 + r];
        int i = i0 + quad * 4 + r;
        ows[(size_t)((bb << 11) + i) * 384 + (h << 6) + d] =
            (signed char)(int)rintf(qclip(fdivn((float)s * so, ipa, ripa)));
      }
    }
  }
}

// ---------------- proj (i8 MFMA): [4096,384] @ [384,384]^T * s + bias ----------------
__global__ __launch_bounds__(256)
void gemm_proj(const signed char* __restrict__ A, const signed char* __restrict__ W,
               const float* __restrict__ bias, float* __restrict__ out,
               const float* __restrict__ apa, const float* __restrict__ apw) {
  const int t = threadIdx.x;
  const int w = t >> 6, lane = t & 63;
  const int lm = lane & 15, quad = lane >> 4;
  const int wm = w >> 1, wn = w & 1;
  const int m0 = blockIdx.x * 64 + wm * 32;
  const int n0 = blockIdx.y * 64 + wn * 32;
  i32x4 acc[2][2] = {};
  for (int k0 = 0; k0 < 384; k0 += 64) {
    i32x4 af[2], bf[2];
#pragma unroll
    for (int mt = 0; mt < 2; ++mt)
      af[mt] = *(const i32x4*)(A + (size_t)(m0 + mt * 16 + lm) * 384 + k0 + quad * 16);
#pragma unroll
    for (int nt = 0; nt < 2; ++nt)
      bf[nt] = *(const i32x4*)(W + (size_t)(n0 + nt * 16 + lm) * 384 + k0 + quad * 16);
#pragma unroll
    for (int mt = 0; mt < 2; ++mt)
#pragma unroll
      for (int nt = 0; nt < 2; ++nt)
        acc[mt][nt] = MFMA_I8(af[mt], bf[nt], acc[mt][nt]);
  }
  const float sAB = apa[0] * apw[0];
#pragma unroll
  for (int mt = 0; mt < 2; ++mt) {
#pragma unroll
    for (int nt = 0; nt < 2; ++nt) {
      int cg = n0 + nt * 16 + lm;
#pragma unroll
      for (int r = 0; r < 4; ++r) {
        int m = m0 + mt * 16 + quad * 4 + r;
        out[(size_t)m * 384 + cg] = (float)acc[mt][nt][r] * sAB + bias[cg];
      }
    }
  }
}

extern "C" void kernel_launch(void* const* d_in, const int* in_sizes, int n_in,
                              void* d_out, int out_size, void* d_ws, size_t ws_size,
                              hipStream_t stream) {
  const float* x        = (const float*)d_in[0];
  const float* w_qkv    = (const float*)d_in[1];
  const float* w_proj   = (const float*)d_in[2];
  const float* b_proj   = (const float*)d_in[3];
  const float* a_qkv_w  = (const float*)d_in[4];
  const float* a_qkv_a  = (const float*)d_in[5];
  const float* a_proj_w = (const float*)d_in[6];
  const float* a_proj_a = (const float*)d_in[7];
  const float* a_q      = (const float*)d_in[8];
  const float* a_k      = (const float*)d_in[9];
  const float* a_v      = (const float*)d_in[10];
  const float* a_attn   = (const float*)d_in[11];
  const float* a_attn2  = (const float*)d_in[12];

  char* wsb = (char*)d_ws;
  signed char* xq   = (signed char*)(wsb + 0);        // 4096*384      = 1,572,864 B
  signed char* wqq  = (signed char*)(wsb + 1572864);  // 1152*384      =   442,368 B
  signed char* wpq  = (signed char*)(wsb + 2015232);  //  384*384      =   147,456 B
  signed char* qws  = (signed char*)(wsb + 2162688);  // 12*2048*64    = 1,572,864 B
  signed char* kws  = (signed char*)(wsb + 3735552);  // same
  signed char* vwsT = (signed char*)(wsb + 5308416);  // same, [bh,d,n]
  signed char* ows  = (signed char*)(wsb + 6881280);  // 4096*384      = 1,572,864 B
  float*       E2   = (float*)(wsb + 8454144);        // 256*256 f32   =   262,144 B
  // total ws usage: 8,716,288 bytes

  prep<<<784, 256, 0, stream>>>(x, w_qkv, w_proj, xq, wqq, wpq, E2,
                                a_qkv_a, a_qkv_w, a_proj_w, a_attn);
  gemm_qkv<<<dim3(64, 18), 256, 0, stream>>>(xq, wqq, qws, kws, vwsT,
                                             a_qkv_a, a_qkv_w, a_q, a_k, a_v);
  attn_fused<<<dim3(128, 12), 256, 0, stream>>>(qws, kws, vwsT, E2, ows,
                                                a_q, a_k, a_attn, a_attn2,
                                                a_v, a_proj_a);
  gemm_proj<<<dim3(64, 6), 256, 0, stream>>>(ows, wpq, b_proj, (float*)d_out,
                                             a_proj_a, a_proj_w);
}